// Round 12
// baseline (1169.191 us; speedup 1.0000x reference)
//
#include <hip/hip_runtime.h>
#include <hip/hip_bf16.h>
#include <math.h>

constexpr int NP  = 32768;  // mesh points
constexpr int HH  = 8;      // heads

typedef short bf16x8 __attribute__((ext_vector_type(8)));
typedef float f32x4  __attribute__((ext_vector_type(4)));

__device__ __forceinline__ float gelu_f(float x) {
    return 0.5f * x * (1.0f + erff(x * 0.70710678118654752f));
}

__device__ __forceinline__ unsigned short f2bf(float x) {
    union { float f; unsigned u; } v; v.f = x;
    unsigned r = v.u + 0x7fffu + ((v.u >> 16) & 1u);
    return (unsigned short)(r >> 16);
}

__device__ __forceinline__ float bf2f(unsigned short h) {
    union { unsigned u; float f; } v; v.u = ((unsigned)h) << 16;
    return v.f;
}

// ---------------------------------------------------------------------------
// Weight prep: src [G][K][256] fp32 -> dst [G][256][K] bf16 (transposed)
// ---------------------------------------------------------------------------
__global__ __launch_bounds__(256) void transpose_bf16_k(
    const float* __restrict__ src, unsigned short* __restrict__ dst, int K)
{
    __shared__ float tile[32][33];
    int g = blockIdx.z;
    int k0 = blockIdx.x * 32, c0 = blockIdx.y * 32;
    int tx = threadIdx.x & 31, ty = threadIdx.x >> 5;
    const float* s = src + (size_t)g * K * 256;
    unsigned short* d = dst + (size_t)g * 256 * K;
    #pragma unroll
    for (int rr = 0; rr < 4; ++rr) {
        int r = ty + rr * 8;
        tile[r][tx] = s[(size_t)(k0 + r) * 256 + c0 + tx];
    }
    __syncthreads();
    #pragma unroll
    for (int rr = 0; rr < 4; ++rr) {
        int r = ty + rr * 8;
        d[(size_t)(c0 + r) * K + k0 + tx] = f2bf(tile[tx][r]);
    }
}

// Same, but scales row k by g[z*256+k] before rounding (LN-fold weights g.W)
__global__ __launch_bounds__(256) void transpose_scale_bf16_k(
    const float* __restrict__ src, const float* __restrict__ g,
    unsigned short* __restrict__ dst, int K)
{
    __shared__ float tile[32][33];
    int z = blockIdx.z;
    int k0 = blockIdx.x * 32, c0 = blockIdx.y * 32;
    int tx = threadIdx.x & 31, ty = threadIdx.x >> 5;
    const float* s = src + (size_t)z * K * 256;
    unsigned short* d = dst + (size_t)z * 256 * K;
    #pragma unroll
    for (int rr = 0; rr < 4; ++rr) {
        int r = ty + rr * 8;
        tile[r][tx] = s[(size_t)(k0 + r) * 256 + c0 + tx];
    }
    __syncthreads();
    float gs = g[z * 256 + k0 + tx];
    #pragma unroll
    for (int rr = 0; rr < 4; ++rr) {
        int r = ty + rr * 8;
        d[(size_t)(c0 + r) * K + k0 + tx] = f2bf(gs * tile[tx][r]);
    }
}

// c2[z][c] = sum_k g[z][k] W[z][k][c] ; c1[z][c] = sum_k b[z][k] W[z][k][c]
__global__ __launch_bounds__(256) void colsum_k(
    const float* __restrict__ W, const float* __restrict__ g,
    const float* __restrict__ b, float* __restrict__ c2, float* __restrict__ c1)
{
    int z = blockIdx.z, c = threadIdx.x;
    const float* Wz = W + (size_t)z * 65536;
    const float* gz = g + z * 256;
    const float* bz = b + z * 256;
    float s2 = 0.f, s1 = 0.f;
    for (int k = 0; k < 256; ++k) {
        float w = Wz[k * 256 + c];
        s2 += gz[k] * w;
        s1 += bz[k] * w;
    }
    c2[z * 256 + c] = s2;
    c1[z * 256 + c] = s1;
}

// wkT[l][d][k]=bf16(wk[l][k][d]); wvT[l][c][k]=bf16(wv[l][k][c]);
// wqT[l][d][k]=bf16(wq[l][k][d])
__global__ __launch_bounds__(256) void prep_wkvT(
    const float* __restrict__ wk, const float* __restrict__ wv,
    const float* __restrict__ wq,
    unsigned short* __restrict__ wkT, unsigned short* __restrict__ wvT,
    unsigned short* __restrict__ wqT)
{
    int l = blockIdx.x, tid = threadIdx.x;
    for (int idx = tid; idx < 4096; idx += 256) {
        int d = idx >> 5, k = idx & 31;
        wkT[l * 4096 + idx] = f2bf(wk[l * 4096 + k * 128 + d]);
        wqT[l * 4096 + idx] = f2bf(wq[l * 4096 + k * 128 + d]);
    }
    for (int idx = tid; idx < 1024; idx += 256) {
        int c = idx >> 5, k = idx & 31;
        wvT[l * 1024 + idx] = f2bf(wv[l * 1024 + k * 32 + c]);
    }
}

// ---------------------------------------------------------------------------
// gena_lgl: fused preprocess + layer-0 xm producer (R7 proven).
// ---------------------------------------------------------------------------
__global__ __launch_bounds__(256) void gena_lgl(
    const float* __restrict__ genx, const float* __restrict__ genw1,
    const float* __restrict__ genb1,
    const unsigned short* __restrict__ W2t, const float* __restrict__ b2,
    const float* __restrict__ ph,
    float* __restrict__ fx,
    const unsigned short* __restrict__ W3t, const float* __restrict__ b3,
    const float* __restrict__ c1n, const float* __restrict__ c2n,
    unsigned short* __restrict__ outNext)
{
    __shared__ __align__(16) unsigned char tpool[32768];  // {w1s,b1s,x3s} -> Ts
    __shared__ __align__(16) unsigned short As[64 * 64];
    __shared__ __align__(16) unsigned short Bs[256 * 64];
    __shared__ float rmean[64];
    __shared__ float rrstd[64];
    __shared__ float ssum[256];
    __shared__ float ssq[256];

    float* w1s = (float*)tpool;                    // 1536 f
    float* b1s = (float*)(tpool + 6144);           // 512 f
    float* x3s = (float*)(tpool + 8192);           // 64 rows * 4
    unsigned short* Ts = (unsigned short*)tpool;   // 64*256 bf16 (post-P1)

    const int tid = threadIdx.x;
    const int rBase = blockIdx.x * 64;
    const int lane = tid & 63, wid = tid >> 6;     // wid = column quarter 0..3
    const int lrow = lane & 15, quad = lane >> 4;

    for (int i2 = tid; i2 < 1536; i2 += 256) w1s[i2] = genw1[i2];
    for (int i2 = tid; i2 < 512; i2 += 256) b1s[i2] = genb1[i2];
    if (tid < 64) {
        x3s[tid * 4 + 0] = genx[(size_t)(rBase + tid) * 3 + 0];
        x3s[tid * 4 + 1] = genx[(size_t)(rBase + tid) * 3 + 1];
        x3s[tid * 4 + 2] = genx[(size_t)(rBase + tid) * 3 + 2];
    }
    __syncthreads();

    // ---- P1: K=512 GEMM with on-the-fly A generation (once per element) ----
    f32x4 acc[4][4];
    #pragma unroll
    for (int i = 0; i < 4; ++i)
        #pragma unroll
        for (int j = 0; j < 4; ++j) acc[i][j] = (f32x4){0.f, 0.f, 0.f, 0.f};

    for (int kc = 0; kc < 512; kc += 64) {
        #pragma unroll
        for (int it = 0; it < 2; ++it) {
            int idx = tid + it * 256;
            int row = idx >> 3, sch = idx & 7;
            float x0 = x3s[row * 4 + 0], x1 = x3s[row * 4 + 1], x2 = x3s[row * 4 + 2];
            unsigned short pk[8];
            #pragma unroll
            for (int j = 0; j < 8; ++j) {
                int k = kc + sch * 8 + j;
                float t = x0 * w1s[k] + x1 * w1s[512 + k] + x2 * w1s[1024 + k] + b1s[k];
                pk[j] = f2bf(gelu_f(t));
            }
            *(uint4*)&As[row * 64 + ((sch ^ (row & 7)) << 3)] = *(uint4*)pk;
        }
        #pragma unroll
        for (int it = 0; it < 8; ++it) {
            int idx = tid + it * 256;
            int n = idx >> 3, sch = idx & 7;
            uint4 wv_ = *(const uint4*)(W2t + (size_t)n * 512 + kc + sch * 8);
            *(uint4*)&Bs[n * 64 + ((sch ^ (n & 7)) << 3)] = wv_;
        }
        __syncthreads();
        #pragma unroll
        for (int ks = 0; ks < 2; ++ks) {
            bf16x8 af[4], bfr[4];
            #pragma unroll
            for (int t = 0; t < 4; ++t) {
                int row = t * 16 + lrow;
                af[t] = *(bf16x8*)&As[row * 64 + (((ks * 4 + quad) ^ (row & 7)) << 3)];
                int n = wid * 64 + t * 16 + lrow;
                bfr[t] = *(bf16x8*)&Bs[n * 64 + (((ks * 4 + quad) ^ (n & 7)) << 3)];
            }
            #pragma unroll
            for (int ti = 0; ti < 4; ++ti)
                #pragma unroll
                for (int tj = 0; tj < 4; ++tj)
                    acc[ti][tj] = __builtin_amdgcn_mfma_f32_16x16x32_bf16(
                        af[ti], bfr[tj], acc[ti][tj], 0, 0, 0);
        }
        __syncthreads();
    }

    // epilogue: fx = acc + (pre_b2 + ph); in-block stats; park bf16 in Ts
    {
        float c1b[4];
        #pragma unroll
        for (int tj = 0; tj < 4; ++tj) {
            int gcol = wid * 64 + tj * 16 + lrow;
            c1b[tj] = b2[gcol] + ph[gcol];
        }
        #pragma unroll
        for (int ti = 0; ti < 4; ++ti) {
            #pragma unroll
            for (int r = 0; r < 4; ++r) {
                int row = ti * 16 + quad * 4 + r;
                int grow = rBase + row;
                float vv[4];
                #pragma unroll
                for (int tj = 0; tj < 4; ++tj)
                    vv[tj] = acc[ti][tj][r] + c1b[tj];
                float rs = vv[0] + vv[1] + vv[2] + vv[3];
                float rq = vv[0]*vv[0] + vv[1]*vv[1] + vv[2]*vv[2] + vv[3]*vv[3];
                #pragma unroll
                for (int m = 1; m < 16; m <<= 1) {
                    rs += __shfl_xor(rs, m);
                    rq += __shfl_xor(rq, m);
                }
                if (lrow == 0) { ssum[row * 4 + wid] = rs; ssq[row * 4 + wid] = rq; }
                #pragma unroll
                for (int tj = 0; tj < 4; ++tj) {
                    int gcol = wid * 64 + tj * 16 + lrow;
                    fx[(size_t)grow * 256 + gcol] = vv[tj];
                    int ch = gcol >> 3;
                    Ts[row * 256 + ((ch ^ (row & 7)) << 3) + (gcol & 7)] = f2bf(vv[tj]);
                }
            }
        }
    }
    __syncthreads();
    if (tid < 64) {
        float mean = (ssum[tid*4+0] + ssum[tid*4+1] + ssum[tid*4+2] + ssum[tid*4+3]) * (1.f/256.f);
        float ex2  = (ssq [tid*4+0] + ssq [tid*4+1] + ssq [tid*4+2] + ssq [tid*4+3]) * (1.f/256.f);
        rmean[tid] = mean;
        rrstd[tid] = rsqrtf(fmaxf(ex2 - mean * mean, 0.f) + 1e-5f);
    }
    __syncthreads();

    // ---- P3: xm0 = LNfold(fx) @ W3 + fold(b3,c1n,c2n), PERM write ----
    f32x4 acc3[4][4];
    #pragma unroll
    for (int i = 0; i < 4; ++i)
        #pragma unroll
        for (int j = 0; j < 4; ++j) acc3[i][j] = (f32x4){0.f, 0.f, 0.f, 0.f};

    for (int kc = 0; kc < 256; kc += 64) {
        #pragma unroll
        for (int it = 0; it < 8; ++it) {
            int idx = tid + it * 256;
            int n = idx >> 3, sch = idx & 7;
            uint4 wv_ = *(const uint4*)(W3t + (size_t)n * 256 + kc + sch * 8);
            *(uint4*)&Bs[n * 64 + ((sch ^ (n & 7)) << 3)] = wv_;
        }
        __syncthreads();
        #pragma unroll
        for (int ks = 0; ks < 2; ++ks) {
            bf16x8 af[4], bfr[4];
            #pragma unroll
            for (int t = 0; t < 4; ++t) {
                int row = t * 16 + lrow;
                int ch = (kc >> 3) + ks * 4 + quad;
                af[t] = *(bf16x8*)&Ts[row * 256 + ((ch ^ (row & 7)) << 3)];
                int n = wid * 64 + t * 16 + lrow;
                bfr[t] = *(bf16x8*)&Bs[n * 64 + (((ks * 4 + quad) ^ (n & 7)) << 3)];
            }
            #pragma unroll
            for (int ti = 0; ti < 4; ++ti)
                #pragma unroll
                for (int tj = 0; tj < 4; ++tj)
                    acc3[ti][tj] = __builtin_amdgcn_mfma_f32_16x16x32_bf16(
                        af[ti], bfr[tj], acc3[ti][tj], 0, 0, 0);
        }
        __syncthreads();
    }

    float c1b3[4], c2r3[4];
    #pragma unroll
    for (int tj = 0; tj < 4; ++tj) {
        int gcol = wid * 64 + tj * 16 + lrow;
        c1b3[tj] = c1n[gcol] + b3[gcol];
        c2r3[tj] = c2n[gcol];
    }
    #pragma unroll
    for (int ti = 0; ti < 4; ++ti) {
        #pragma unroll
        for (int r = 0; r < 4; ++r) {
            int row = ti * 16 + quad * 4 + r;
            int grow = rBase + row;
            float mean = rmean[row], rstd = rrstd[row];
            #pragma unroll
            for (int tj = 0; tj < 4; ++tj) {
                int gcol = wid * 64 + tj * 16 + lrow;
                float t = acc3[ti][tj][r];
                float v = rstd * (t - mean * c2r3[tj]) + c1b3[tj];
                size_t pidx = (size_t)(gcol >> 5) * NP * 32 + (size_t)grow * 32 + (gcol & 31);
                outNext[pidx] = f2bf(v);
            }
        }
    }
}

// ---------------------------------------------------------------------------
// attn_lgl: fused qkv + attn-out pair (R6/R7/R10 proven). Per 64-row block:
//   P0  per-head qkv -> Dt bf16 into Ts (LDS)
//   P1  T1 = GELU(Dt @ O1 + ob1)          (Ts -> Ts)
//   P2  fx += T1 @ O2 + ob2  (+LN2 stats -> global st)
// ---------------------------------------------------------------------------
__global__ __launch_bounds__(256) void attn_lgl(
    const unsigned short* __restrict__ xm, const unsigned short* __restrict__ wqT,
    const float* __restrict__ tq_arr,
    const unsigned short* __restrict__ kvT, const float* __restrict__ sumexp,
    const unsigned short* __restrict__ O1t, const float* __restrict__ ob1,
    const unsigned short* __restrict__ O2t, const float* __restrict__ ob2,
    float* __restrict__ fx, float* __restrict__ stats_out, int layer)
{
    __shared__ __align__(16) unsigned char upool[38912];
    __shared__ __align__(16) unsigned short Ts[64 * 256];

    unsigned short* xs  = (unsigned short*)(upool);           // 64*32
    unsigned short* wqs = (unsigned short*)(upool + 4096);    // 128*32
    unsigned short* kvb = (unsigned short*)(upool + 12288);   // 32*136
    unsigned short* els = (unsigned short*)(upool + 20992);   // 64*136
    float*          ises = (float*)(upool + 38400);           // 128
    unsigned short* Bs  = (unsigned short*)(upool);           // 256*64 (P1/P2)

    const int tid = threadIdx.x;
    const int rBase = blockIdx.x * 64;
    const int lane = tid & 63, wid = tid >> 6;
    const int lrow = lane & 15, quad = lane >> 4;

    // ---- P0: qkv per head -> Ts ----
    #pragma unroll
    for (int it = 0; it < 2; ++it) {           // wq shared across heads
        int cid = tid + it * 256;
        int d = cid >> 2, kc = cid & 3;
        uint4 v = *(const uint4*)(wqT + d * 32 + kc * 8);
        *(uint4*)&wqs[d * 32 + ((kc ^ (d & 3)) << 3)] = v;
    }
    for (int h = 0; h < 8; ++h) {
        if (h) __syncthreads();                // prev head's reads done
        float tq = fminf(fmaxf(tq_arr[layer * 8 + h], 0.1f), 2.0f);
        float invtq = 1.0f / tq;
        if (tid < 128) ises[tid] = 1.0f / sumexp[h * 128 + tid];
        #pragma unroll
        for (int it = 0; it < 2; ++it) {
            int cid = tid + it * 256;
            int c = cid >> 4, k8 = cid & 15;
            uint4 v = *(const uint4*)(kvT + (size_t)h * 4096 + c * 128 + k8 * 8);
            *(uint4*)&kvb[c * 136 + k8 * 8] = v;
        }
        {
            int row = tid >> 2, kc = tid & 3;
            uint4 v = *(const uint4*)(xm + (size_t)h * NP * 32 +
                                      (size_t)(rBase + row) * 32 + kc * 8);
            *(uint4*)&xs[row * 32 + ((kc ^ (row & 3)) << 3)] = v;
        }
        __syncthreads();

        int arow = wid * 16 + lrow;
        bf16x8 ax = *(bf16x8*)&xs[arow * 32 + ((quad ^ (arow & 3)) << 3)];
        f32x4 lg[8];
        #pragma unroll
        for (int dt = 0; dt < 8; ++dt) {
            int d = dt * 16 + lrow;
            bf16x8 bw = *(bf16x8*)&wqs[d * 32 + ((quad ^ (d & 3)) << 3)];
            f32x4 cc = (f32x4){0.f, 0.f, 0.f, 0.f};
            lg[dt] = __builtin_amdgcn_mfma_f32_16x16x32_bf16(ax, bw, cc, 0, 0, 0);
        }
        float isv[8];
        #pragma unroll
        for (int dt = 0; dt < 8; ++dt) isv[dt] = ises[dt * 16 + lrow];

        #pragma unroll
        for (int r = 0; r < 4; ++r) {
            float m = lg[0][r];
            #pragma unroll
            for (int dt = 1; dt < 8; ++dt) m = fmaxf(m, lg[dt][r]);
            m = fmaxf(m, __shfl_xor(m, 1));
            m = fmaxf(m, __shfl_xor(m, 2));
            m = fmaxf(m, __shfl_xor(m, 4));
            m = fmaxf(m, __shfl_xor(m, 8));
            float e[8], s = 0.f;
            #pragma unroll
            for (int dt = 0; dt < 8; ++dt) {
                e[dt] = __expf((lg[dt][r] - m) * invtq);
                s += e[dt];
            }
            s += __shfl_xor(s, 1);
            s += __shfl_xor(s, 2);
            s += __shfl_xor(s, 4);
            s += __shfl_xor(s, 8);
            float inv = 1.0f / s;
            int erow = wid * 16 + quad * 4 + r;
            #pragma unroll
            for (int dt = 0; dt < 8; ++dt)
                els[erow * 136 + dt * 16 + lrow] = f2bf(e[dt] * inv * isv[dt]);
        }

        #pragma unroll
        for (int ct = 0; ct < 2; ++ct) {
            f32x4 oc = (f32x4){0.f, 0.f, 0.f, 0.f};
            #pragma unroll
            for (int ks = 0; ks < 4; ++ks) {
                bf16x8 ae = *(bf16x8*)&els[(wid * 16 + lrow) * 136 + ks * 32 + quad * 8];
                bf16x8 bv = *(bf16x8*)&kvb[(ct * 16 + lrow) * 136 + ks * 32 + quad * 8];
                oc = __builtin_amdgcn_mfma_f32_16x16x32_bf16(ae, bv, oc, 0, 0, 0);
            }
            #pragma unroll
            for (int r = 0; r < 4; ++r) {
                int row = wid * 16 + quad * 4 + r;
                int col = h * 32 + ct * 16 + lrow;
                int ch = col >> 3;
                Ts[row * 256 + ((ch ^ (row & 7)) << 3) + (col & 7)] = f2bf(oc[r]);
            }
        }
    }
    __syncthreads();

    // ---- shared GEMM phase: acc += Ts(bf16) @ Wt ----
    auto gemm_phase = [&](const unsigned short* __restrict__ Wt, f32x4 (&acc)[4][4]) {
        for (int kc = 0; kc < 256; kc += 64) {
            #pragma unroll
            for (int it = 0; it < 8; ++it) {
                int idx = tid + it * 256;
                int n = idx >> 3, sch = idx & 7;
                uint4 wv_ = *(const uint4*)(Wt + (size_t)n * 256 + kc + sch * 8);
                *(uint4*)&Bs[n * 64 + ((sch ^ (n & 7)) << 3)] = wv_;
            }
            __syncthreads();
            #pragma unroll
            for (int ks = 0; ks < 2; ++ks) {
                bf16x8 af[4], bfr[4];
                #pragma unroll
                for (int t = 0; t < 4; ++t) {
                    int row = t * 16 + lrow;
                    int ch = (kc >> 3) + ks * 4 + quad;
                    af[t] = *(bf16x8*)&Ts[row * 256 + ((ch ^ (row & 7)) << 3)];
                    int n = wid * 64 + t * 16 + lrow;
                    bfr[t] = *(bf16x8*)&Bs[n * 64 + (((ks * 4 + quad) ^ (n & 7)) << 3)];
                }
                #pragma unroll
                for (int ti = 0; ti < 4; ++ti)
                    #pragma unroll
                    for (int tj = 0; tj < 4; ++tj)
                        acc[ti][tj] = __builtin_amdgcn_mfma_f32_16x16x32_bf16(
                            af[ti], bfr[tj], acc[ti][tj], 0, 0, 0);
            }
            __syncthreads();
        }
    };

    // ---- P1: T1 = GELU(Dt @ O1 + ob1) ----
    f32x4 acc[4][4];
    #pragma unroll
    for (int i = 0; i < 4; ++i)
        #pragma unroll
        for (int j = 0; j < 4; ++j) acc[i][j] = (f32x4){0.f, 0.f, 0.f, 0.f};
    gemm_phase(O1t, acc);
    {
        float c1b[4];
        #pragma unroll
        for (int tj = 0; tj < 4; ++tj) c1b[tj] = ob1[wid * 64 + tj * 16 + lrow];
        #pragma unroll
        for (int ti = 0; ti < 4; ++ti) {
            #pragma unroll
            for (int r = 0; r < 4; ++r) {
                int row = ti * 16 + quad * 4 + r;
                #pragma unroll
                for (int tj = 0; tj < 4; ++tj) {
                    float v = gelu_f(acc[ti][tj][r] + c1b[tj]);
                    int col = wid * 64 + tj * 16 + lrow;
                    int ch = col >> 3;
                    Ts[row * 256 + ((ch ^ (row & 7)) << 3) + (col & 7)] = f2bf(v);
                }
            }
        }
    }
    __syncthreads();

    // ---- P2: fx += T1 @ O2 + ob2 (+LN2 stats -> global) ----
    #pragma unroll
    for (int i = 0; i < 4; ++i)
        #pragma unroll
        for (int j = 0; j < 4; ++j) acc[i][j] = (f32x4){0.f, 0.f, 0.f, 0.f};
    gemm_phase(O2t, acc);
    {
        float bb[4];
        #pragma unroll
        for (int tj = 0; tj < 4; ++tj) bb[tj] = ob2[wid * 64 + tj * 16 + lrow];
        #pragma unroll
        for (int ti = 0; ti < 4; ++ti) {
            #pragma unroll
            for (int r = 0; r < 4; ++r) {
                int row = ti * 16 + quad * 4 + r;
                int grow = rBase + row;
                float vv[4];
                #pragma unroll
                for (int tj = 0; tj < 4; ++tj) {
                    int gcol = wid * 64 + tj * 16 + lrow;
                    vv[tj] = acc[ti][tj][r] + bb[tj] + fx[(size_t)grow * 256 + gcol];
                }
                float rs = vv[0] + vv[1] + vv[2] + vv[3];
                float rq = vv[0]*vv[0] + vv[1]*vv[1] + vv[2]*vv[2] + vv[3]*vv[3];
                #pragma unroll
                for (int m = 1; m < 16; m <<= 1) {
                    rs += __shfl_xor(rs, m);
                    rq += __shfl_xor(rq, m);
                }
                if (lrow == 0) {
                    stats_out[(size_t)grow * 8 + wid * 2 + 0] = rs;
                    stats_out[(size_t)grow * 8 + wid * 2 + 1] = rq;
                }
                #pragma unroll
                for (int tj = 0; tj < 4; ++tj) {
                    int gcol = wid * 64 + tj * 16 + lrow;
                    fx[(size_t)grow * 256 + gcol] = vv[tj];
                }
            }
        }
    }
}

// ---------------------------------------------------------------------------
// Fused Linear->GELU->Linear (+ optional next-layer xm2h producer) — R3 proven.
//   fx += GELU((LN?)A @ W1 + b1) @ W2 + b2          [phase 1+2]
//   if NEXTW: xm2h = perm(LNfold(fx) @ W3 + b3)      [phase 3, in-block LN]
// ---------------------------------------------------------------------------
template<bool AF32, bool LNFOLD, bool WSTATS, bool NEXTW>
__global__ __launch_bounds__(256) void gemm_lgl(
    const unsigned short* __restrict__ Ah, const float* __restrict__ Af,
    const unsigned short* __restrict__ W1t, const unsigned short* __restrict__ W2t,
    const float* __restrict__ b1, const float* __restrict__ b2,
    float* __restrict__ fx,
    const float* __restrict__ stats_in, float* __restrict__ stats_out,
    const float* __restrict__ c1v, const float* __restrict__ c2vec,
    const unsigned short* __restrict__ W3t, const float* __restrict__ b3,
    const float* __restrict__ c1n, const float* __restrict__ c2n,
    unsigned short* __restrict__ outNext)
{
    __shared__ __align__(16) unsigned short As[64 * 64];
    __shared__ __align__(16) unsigned short Bs[256 * 64];
    __shared__ __align__(16) unsigned short Ts[64 * 256];
    __shared__ float rmean[(LNFOLD || NEXTW) ? 64 : 1];
    __shared__ float rrstd[(LNFOLD || NEXTW) ? 64 : 1];
    __shared__ float ssum[NEXTW ? 256 : 1];
    __shared__ float ssq [NEXTW ? 256 : 1];

    const int tid = threadIdx.x;
    const int rBase = blockIdx.x * 64;
    const int lane = tid & 63, wid = tid >> 6;   // wid = column quarter 0..3
    const int lrow = lane & 15, quad = lane >> 4;

    if constexpr (LNFOLD) {
        if (tid < 64) {
            const float* sp = stats_in + (size_t)(rBase + tid) * 8;
            float4 s0 = *(const float4*)sp;
            float4 s1 = *(const float4*)(sp + 4);
            float mean = (s0.x + s0.z + s1.x + s1.z) * (1.f / 256.f);
            float ex2  = (s0.y + s0.w + s1.y + s1.w) * (1.f / 256.f);
            rmean[tid] = mean;
            rrstd[tid] = rsqrtf(fmaxf(ex2 - mean * mean, 0.f) + 1e-5f);
        }
    }

    f32x4 acc[4][4];
    #pragma unroll
    for (int i = 0; i < 4; ++i)
        #pragma unroll
        for (int j = 0; j < 4; ++j)
            acc[i][j] = (f32x4){0.f, 0.f, 0.f, 0.f};

    // ---- phase 1: T = GELU((LN?)A @ W1 + b1) ----
    for (int kc = 0; kc < 256; kc += 64) {
        #pragma unroll
        for (int it = 0; it < 2; ++it) {
            int idx = tid + it * 256;
            int row = idx >> 3, sch = idx & 7;
            if constexpr (AF32) {
                const float* ap = Af + (size_t)(rBase + row) * 256 + kc + sch * 8;
                float4 a0 = *(const float4*)ap;
                float4 a1 = *(const float4*)(ap + 4);
                unsigned short pk[8];
                pk[0] = f2bf(a0.x); pk[1] = f2bf(a0.y); pk[2] = f2bf(a0.z); pk[3] = f2bf(a0.w);
                pk[4] = f2bf(a1.x); pk[5] = f2bf(a1.y); pk[6] = f2bf(a1.z); pk[7] = f2bf(a1.w);
                *(uint4*)&As[row * 64 + ((sch ^ (row & 7)) << 3)] = *(uint4*)pk;
            } else {
                uint4 av = *(const uint4*)(Ah + (size_t)(rBase + row) * 256 + kc + sch * 8);
                *(uint4*)&As[row * 64 + ((sch ^ (row & 7)) << 3)] = av;
            }
        }
        #pragma unroll
        for (int it = 0; it < 8; ++it) {
            int idx = tid + it * 256;
            int n = idx >> 3, sch = idx & 7;
            uint4 wv_ = *(const uint4*)(W1t + (size_t)n * 256 + kc + sch * 8);
            *(uint4*)&Bs[n * 64 + ((sch ^ (n & 7)) << 3)] = wv_;
        }
        __syncthreads();
        #pragma unroll
        for (int ks = 0; ks < 2; ++ks) {
            bf16x8 af[4], bfr[4];
            #pragma unroll
            for (int t = 0; t < 4; ++t) {
                int row = t * 16 + lrow;
                af[t] = *(bf16x8*)&As[row * 64 + (((ks * 4 + quad) ^ (row & 7)) << 3)];
                int n = wid * 64 + t * 16 + lrow;
                bfr[t] = *(bf16x8*)&Bs[n * 64 + (((ks * 4 + quad) ^ (n & 7)) << 3)];
            }
            #pragma unroll
            for (int ti = 0; ti < 4; ++ti)
                #pragma unroll
                for (int tj = 0; tj < 4; ++tj)
                    acc[ti][tj] = __builtin_amdgcn_mfma_f32_16x16x32_bf16(
                        af[ti], bfr[tj], acc[ti][tj], 0, 0, 0);
        }
        __syncthreads();
    }

    // epilogue 1: bias (+LN-fold) + GELU -> Ts (bf16, chunk-XOR swizzled)
    {
        float c1b[4], c2r[4];
        #pragma unroll
        for (int tj = 0; tj < 4; ++tj) {
            int gcol = wid * 64 + tj * 16 + lrow;
            if constexpr (LNFOLD) {
                c1b[tj] = c1v[gcol] + b1[gcol];
                c2r[tj] = c2vec[gcol];
            } else {
                c1b[tj] = b1[gcol];
                c2r[tj] = 0.f;
            }
        }
        #pragma unroll
        for (int ti = 0; ti < 4; ++ti) {
            #pragma unroll
            for (int r = 0; r < 4; ++r) {
                int row = ti * 16 + quad * 4 + r;
                float mean = 0.f, rstd = 1.f;
                if constexpr (LNFOLD) { mean = rmean[row]; rstd = rrstd[row]; }
                #pragma unroll
                for (int tj = 0; tj < 4; ++tj) {
                    float t = acc[ti][tj][r];
                    float v;
                    if constexpr (LNFOLD) v = rstd * (t - mean * c2r[tj]) + c1b[tj];
                    else                  v = t + c1b[tj];
                    v = gelu_f(v);
                    int col = wid * 64 + tj * 16 + lrow;
                    int ch = col >> 3;
                    Ts[row * 256 + ((ch ^ (row & 7)) << 3) + (col & 7)] = f2bf(v);
                }
            }
        }
    }
    __syncthreads();

    // ---- phase 2: out = T @ W2 + b2 (+resid); A comes from LDS ----
    f32x4 acc2[4][4];
    #pragma unroll
    for (int i = 0; i < 4; ++i)
        #pragma unroll
        for (int j = 0; j < 4; ++j)
            acc2[i][j] = (f32x4){0.f, 0.f, 0.f, 0.f};

    for (int kc = 0; kc < 256; kc += 64) {
        #pragma unroll
        for (int it = 0; it < 8; ++it) {
            int idx = tid + it * 256;
            int n = idx >> 3, sch = idx & 7;
            uint4 wv_ = *(const uint4*)(W2t + (size_t)n * 256 + kc + sch * 8);
            *(uint4*)&Bs[n * 64 + ((sch ^ (n & 7)) << 3)] = wv_;
        }
        __syncthreads();
        #pragma unroll
        for (int ks = 0; ks < 2; ++ks) {
            bf16x8 af[4], bfr[4];
            #pragma unroll
            for (int t = 0; t < 4; ++t) {
                int row = t * 16 + lrow;
                int ch = (kc >> 3) + ks * 4 + quad;
                af[t] = *(bf16x8*)&Ts[row * 256 + ((ch ^ (row & 7)) << 3)];
                int n = wid * 64 + t * 16 + lrow;
                bfr[t] = *(bf16x8*)&Bs[n * 64 + (((ks * 4 + quad) ^ (n & 7)) << 3)];
            }
            #pragma unroll
            for (int ti = 0; ti < 4; ++ti)
                #pragma unroll
                for (int tj = 0; tj < 4; ++tj)
                    acc2[ti][tj] = __builtin_amdgcn_mfma_f32_16x16x32_bf16(
                        af[ti], bfr[tj], acc2[ti][tj], 0, 0, 0);
        }
        __syncthreads();
    }

    // epilogue 2: +b2, +resid(fx), store fx fp32; optional stats (global or LDS)
    float bb[4];
    #pragma unroll
    for (int tj = 0; tj < 4; ++tj) bb[tj] = b2[wid * 64 + tj * 16 + lrow];
    #pragma unroll
    for (int ti = 0; ti < 4; ++ti) {
        #pragma unroll
        for (int r = 0; r < 4; ++r) {
            int row = ti * 16 + quad * 4 + r;
            int grow = rBase + row;
            float vv[4];
            #pragma unroll
            for (int tj = 0; tj < 4; ++tj) {
                int gcol = wid * 64 + tj * 16 + lrow;
                vv[tj] = acc2[ti][tj][r] + bb[tj] + fx[(size_t)grow * 256 + gcol];
            }
            if constexpr (WSTATS || NEXTW) {
                float rs = vv[0] + vv[1] + vv[2] + vv[3];
                float rq = vv[0]*vv[0] + vv[1]*vv[1] + vv[2]*vv[2] + vv[3]*vv[3];
                #pragma unroll
                for (int m = 1; m < 16; m <<= 1) {
                    rs += __shfl_xor(rs, m);
                    rq += __shfl_xor(rq, m);
                }
                if (lrow == 0) {
                    if constexpr (WSTATS) {
                        stats_out[(size_t)grow * 8 + wid * 2 + 0] = rs;
                        stats_out[(size_t)grow * 8 + wid * 2 + 1] = rq;
                    }
                    if constexpr (NEXTW) {
                        ssum[row * 4 + wid] = rs;
                        ssq [row * 4 + wid] = rq;
                    }
                }
            }
            #pragma unroll
            for (int tj = 0; tj < 4; ++tj) {
                int gcol = wid * 64 + tj * 16 + lrow;
                fx[(size_t)grow * 256 + gcol] = vv[tj];
                if constexpr (NEXTW) {
                    int ch = gcol >> 3;
                    Ts[row * 256 + ((ch ^ (row & 7)) << 3) + (gcol & 7)] = f2bf(vv[tj]);
                }
            }
        }
    }

    if constexpr (NEXTW) {
        __syncthreads();
        if (tid < 64) {
            float mean = (ssum[tid*4+0] + ssum[tid*4+1] + ssum[tid*4+2] + ssum[tid*4+3]) * (1.f/256.f);
            float ex2  = (ssq [tid*4+0] + ssq [tid*4+1] + ssq [tid*4+2] + ssq [tid*4+3]) * (1.f/256.f);
            rmean[tid] = mean;
            rrstd[tid] = rsqrtf(fmaxf(ex2 - mean * mean, 0.f) + 1e-5f);
        }
        __syncthreads();

        // ---- phase 3: xm2h = LNfold(fx) @ W3 + fold(b3,c1n,c2n), PERM write ----
        f32x4 acc3[4][4];
        #pragma unroll
        for (int i = 0; i < 4; ++i)
            #pragma unroll
            for (int j = 0; j < 4; ++j)
                acc3[i][j] = (f32x4){0.f, 0.f, 0.f, 0.f};

        for (int kc = 0; kc < 256; kc += 64) {
            #pragma unroll
            for (int it = 0; it < 8; ++it) {
                int idx = tid + it * 256;
                int n = idx >> 3, sch = idx & 7;
                uint4 wv_ = *(const uint4*)(W3t + (size_t)n * 256 + kc + sch * 8);
                *(uint4*)&Bs[n * 64 + ((sch ^ (n & 7)) << 3)] = wv_;
            }
            __syncthreads();
            #pragma unroll
            for (int ks = 0; ks < 2; ++ks) {
                bf16x8 af[4], bfr[4];
                #pragma unroll
                for (int t = 0; t < 4; ++t) {
                    int row = t * 16 + lrow;
                    int ch = (kc >> 3) + ks * 4 + quad;
                    af[t] = *(bf16x8*)&Ts[row * 256 + ((ch ^ (row & 7)) << 3)];
                    int n = wid * 64 + t * 16 + lrow;
                    bfr[t] = *(bf16x8*)&Bs[n * 64 + (((ks * 4 + quad) ^ (n & 7)) << 3)];
                }
                #pragma unroll
                for (int ti = 0; ti < 4; ++ti)
                    #pragma unroll
                    for (int tj = 0; tj < 4; ++tj)
                        acc3[ti][tj] = __builtin_amdgcn_mfma_f32_16x16x32_bf16(
                            af[ti], bfr[tj], acc3[ti][tj], 0, 0, 0);
            }
            __syncthreads();
        }

        float c1b3[4], c2r3[4];
        #pragma unroll
        for (int tj = 0; tj < 4; ++tj) {
            int gcol = wid * 64 + tj * 16 + lrow;
            c1b3[tj] = c1n[gcol] + b3[gcol];
            c2r3[tj] = c2n[gcol];
        }
        #pragma unroll
        for (int ti = 0; ti < 4; ++ti) {
            #pragma unroll
            for (int r = 0; r < 4; ++r) {
                int row = ti * 16 + quad * 4 + r;
                int grow = rBase + row;
                float mean = rmean[row], rstd = rrstd[row];
                #pragma unroll
                for (int tj = 0; tj < 4; ++tj) {
                    int gcol = wid * 64 + tj * 16 + lrow;
                    float t = acc3[ti][tj][r];
                    float v = rstd * (t - mean * c2r3[tj]) + c1b3[tj];
                    size_t pidx = (size_t)(gcol >> 5) * NP * 32 + (size_t)grow * 32 + (gcol & 31);
                    outNext[pidx] = f2bf(v);
                }
            }
        }
    }
}

// ---------------------------------------------------------------------------
// kv6 (unchanged, working): flash-style MFMA kv.
// ---------------------------------------------------------------------------
__global__ __launch_bounds__(256) void kv6_kernel(
    const unsigned short* __restrict__ xm2h, const unsigned short* __restrict__ wkT,
    const unsigned short* __restrict__ wvT, const float* __restrict__ tk_arr,
    float* __restrict__ partials, int layer)
{
    __shared__ __align__(16) unsigned short xs[64 * 32];
    __shared__ __align__(16) unsigned short wks[128 * 32];
    __shared__ __align__(16) unsigned short wvs[32 * 32];
    __shared__ __align__(16) unsigned short els[128 * 72];
    __shared__ __align__(16) unsigned short vls[32 * 72];
    __shared__ float sums[4 * 128];

    const int tid = threadIdx.x;
    const int h = blockIdx.y;
    const int rowBase = blockIdx.x * 512;
    const int w = tid >> 6, lane = tid & 63;
    const int lrow = lane & 15, quad = lane >> 4;

    float tk = fminf(fmaxf(tk_arr[layer * 8 + h], 0.1f), 2.0f);
    float invtk = 1.0f / tk;

    #pragma unroll
    for (int it = 0; it < 2; ++it) {
        int cid = tid + it * 256;
        int d = cid >> 2, kc = cid & 3;
        uint4 v = *(const uint4*)(wkT + d * 32 + kc * 8);
        *(uint4*)&wks[d * 32 + ((kc ^ (d & 3)) << 3)] = v;
    }
    if (tid < 128) {
        int c = tid >> 2, kc = tid & 3;
        uint4 v = *(const uint4*)(wvT + c * 32 + kc * 8);
        *(uint4*)&wvs[c * 32 + ((kc ^ (c & 3)) << 3)] = v;
    }

    f32x4 acc2[2][2];
    #pragma unroll
    for (int di = 0; di < 2; ++di)
        #pragma unroll
        for (int ci = 0; ci < 2; ++ci)
            acc2[di][ci] = (f32x4){0.f, 0.f, 0.f, 0.f};
    float seacc[8];
    #pragma unroll
    for (int dt = 0; dt < 8; ++dt) seacc[dt] = 0.f;

    const unsigned short* src = xm2h + (size_t)h * NP * 32 + (size_t)rowBase * 32;

    for (int sub = 0; sub < 8; ++sub) {
        __syncthreads();
        {
            int row = tid >> 2, kc = tid & 3;
            uint4 v = *(const uint4*)(src + (size_t)(sub * 64 + row) * 32 + kc * 8);
            *(uint4*)&xs[row * 32 + ((kc ^ (row & 3)) << 3)] = v;
        }
        __syncthreads();
        int arow = w * 16 + lrow;
        bf16x8 ax = *(bf16x8*)&xs[arow * 32 + ((quad ^ (arow & 3)) << 3)];
        #pragma unroll
        for (int ct = 0; ct < 2; ++ct) {
            int c = ct * 16 + lrow;
            bf16x8 bw = *(bf16x8*)&wvs[c * 32 + ((quad ^ (c & 3)) << 3)];
            f32x4 cc = (f32x4){0.f, 0.f, 0.f, 0.f};
            cc = __builtin_amdgcn_mfma_f32_16x16x32_bf16(ax, bw, cc, 0, 0, 0);
            unsigned short pk[4];
            pk[0] = f2bf(cc[0]); pk[1] = f2bf(cc[1]);
            pk[2] = f2bf(cc[2]); pk[3] = f2bf(cc[3]);
            *(uint2*)&vls[(ct * 16 + lrow) * 72 + w * 16 + quad * 4] = *(uint2*)pk;
        }
        #pragma unroll
        for (int dt = 0; dt < 8; ++dt) {
            int d = dt * 16 + lrow;
            bf16x8 bw = *(bf16x8*)&wks[d * 32 + ((quad ^ (d & 3)) << 3)];
            f32x4 cc = (f32x4){0.f, 0.f, 0.f, 0.f};
            cc = __builtin_amdgcn_mfma_f32_16x16x32_bf16(ax, bw, cc, 0, 0, 0);
            unsigned short pk[4];
            float se = 0.f;
            #pragma unroll
            for (int r = 0; r < 4; ++r) {
                float l = fminf(fmaxf(cc[r] * invtk, -30.f), 30.f);
                unsigned short eb = f2bf(__expf(l));
                pk[r] = eb;
                se += bf2f(eb);
            }
            seacc[dt] += se;
            *(uint2*)&els[d * 72 + w * 16 + quad * 4] = *(uint2*)pk;
        }
        __syncthreads();
        #pragma unroll
        for (int di = 0; di < 2; ++di) {
            int dm = (2 * w + di) * 16 + lrow;
            #pragma unroll
            for (int ks = 0; ks < 2; ++ks) {
                bf16x8 ae = *(bf16x8*)&els[dm * 72 + ks * 32 + quad * 8];
                #pragma unroll
                for (int ci = 0; ci < 2; ++ci) {
                    int cn = ci * 16 + lrow;
                    bf16x8 bv = *(bf16x8*)&vls[cn * 72 + ks * 32 + quad * 8];
                    acc2[di][ci] = __builtin_amdgcn_mfma_f32_16x16x32_bf16(
                        ae, bv, acc2[di][ci], 0, 0, 0);
                }
            }
        }
    }

    float* outp = partials + ((size_t)h * 64 + blockIdx.x) * 4224;
    #pragma unroll
    for (int di = 0; di < 2; ++di)
        #pragma unroll
        for (int ci = 0; ci < 2; ++ci)
            #pragma unroll
            for (int r = 0; r < 4; ++r) {
                int d = (2 * w + di) * 16 + quad * 4 + r;
                int c = ci * 16 + lrow;
                outp[d * 32 + c] = acc2[di][ci][r];
            }
    #pragma unroll
    for (int dt = 0; dt < 8; ++dt) {
        float s = seacc[dt];
        s += __shfl_xor(s, 16);
        s += __shfl_xor(s, 32);
        if (quad == 0) sums[w * 128 + dt * 16 + lrow] = s;
    }
    __syncthreads();
    if (tid < 128)
        outp[4096 + tid] = sums[tid] + sums[128 + tid] + sums[256 + tid] + sums[384 + tid];
}

// kv_reduce: emits bf16 kvT[h][c][d] (for qkv's B operand) + sumexp.
__global__ __launch_bounds__(256) void kv_reduce_kernel(
    const float* __restrict__ partials, unsigned short* __restrict__ kvT,
    float* __restrict__ sumexp)
{
    int gid = blockIdx.x * 256 + threadIdx.x;
    if (gid >= 8 * 4224) return;
    int h = gid / 4224, idx = gid % 4224;
    const float* base = partials + (size_t)h * 64 * 4224 + idx;
    float s = 0.f;
    #pragma unroll 8
    for (int c = 0; c < 64; ++c) s += base[(size_t)c * 4224];
    if (idx < 4096) {
        int d = idx >> 5, c = idx & 31;
        kvT[(size_t)h * 4096 + c * 128 + d] = f2bf(s);
    } else {
        sumexp[h * 128 + (idx - 4096)] = s;
    }
}

// ---------------------------------------------------------------------------
// head: out[n] = LN(fx[n]; ln3) . head_w + head_b
// ---------------------------------------------------------------------------
__global__ __launch_bounds__(256) void head_kernel(
    const float* __restrict__ fx, const float* __restrict__ g, const float* __restrict__ b,
    const float* __restrict__ hw, const float* __restrict__ hb, float* __restrict__ out)
{
    int lane = threadIdx.x & 63;
    int row = blockIdx.x * 4 + (threadIdx.x >> 6);
    float4 v = *(const float4*)(fx + (size_t)row * 256 + lane * 4);
    float s1 = v.x + v.y + v.z + v.w;
    float s2 = v.x * v.x + v.y * v.y + v.z * v.z + v.w * v.w;
    #pragma unroll
    for (int m = 1; m < 64; m <<= 1) { s1 += __shfl_xor(s1, m); s2 += __shfl_xor(s2, m); }
    float mean = s1 * 0.00390625f;
    float rstd = rsqrtf(fmaxf(s2 * 0.00390625f - mean * mean, 0.f) + 1e-5f);
    float4 gg = *(const float4*)(g + lane * 4);
    float4 bb = *(const float4*)(b + lane * 4);
    float4 w4 = *(const float4*)(hw + lane * 4);
    float d = ((v.x - mean) * rstd * gg.x + bb.x) * w4.x
            + ((v.y - mean) * rstd * gg.y + bb.y) * w4.y
            + ((v.z - mean) * rstd * gg.z + bb.z) * w4.z
            + ((v.w - mean) * rstd * gg.w + bb.w) * w4.w;
    #pragma unroll
    for (int m = 1; m < 64; m <<= 1) d += __shfl_xor(d, m);
    if (lane == 0) out[row] = d + hb[0];
}

extern "C" void kernel_launch(void* const* d_in, const int* in_sizes, int n_in,
                              void* d_out, int out_size, void* d_ws, size_t ws_size,
                              hipStream_t stream)
{
    const float* x      = (const float*)d_in[0];
    const float* pre_w1 = (const float*)d_in[1];
    const float* pre_b1 = (const float*)d_in[2];
    const float* pre_w2 = (const float*)d_in[3];
    const float* pre_b2 = (const float*)d_in[4];
    const float* ph     = (const float*)d_in[5];
    const float* ln1_g  = (const float*)d_in[6];
    const float* ln1_b  = (const float*)d_in[7];
    const float* inp_w  = (const float*)d_in[8];
    const float* inp_b  = (const float*)d_in[9];
    const float* temp_q = (const float*)d_in[10];
    const float* temp_k = (const float*)d_in[11];
    const float* wq     = (const float*)d_in[12];
    const float* wk     = (const float*)d_in[13];
    const float* wv     = (const float*)d_in[14];
    const float* out_w1 = (const float*)d_in[15];
    const float* out_b1 = (const float*)d_in[16];
    const float* out_w2 = (const float*)d_in[17];
    const float* out_b2 = (const float*)d_in[18];
    const float* ln2_g  = (const float*)d_in[19];
    const float* ln2_b  = (const float*)d_in[20];
    const float* mlp_w1 = (const float*)d_in[21];
    const float* mlp_b1 = (const float*)d_in[22];
    const float* mlp_w2 = (const float*)d_in[23];
    const float* mlp_b2 = (const float*)d_in[24];
    const float* ln3_g  = (const float*)d_in[25];
    const float* ln3_b  = (const float*)d_in[26];
    const float* head_w = (const float*)d_in[27];
    const float* head_b = (const float*)d_in[28];
    float* out = (float*)d_out;

    // ws layout: fx | xmB | xmA | scr | st | kvT | se | cvecs | weights
    float* fx = (float*)d_ws;
    unsigned short* xmB = (unsigned short*)(fx + (size_t)NP * 256);
    unsigned short* xmA = xmB + (size_t)NP * 256;
    float* scr = (float*)(xmA + (size_t)NP * 256);
    float* st = scr + (size_t)NP * 256;
    unsigned short* kvT = (unsigned short*)(st + (size_t)NP * 8);
    float* se = (float*)(kvT + 8 * 4096);
    float* c1i = se + 8 * 128;
    float* c2i = c1i + 1280;
    float* c1m = c2i + 1280;
    float* c2m = c1m + 1280;
    unsigned short* wtPre = (unsigned short*)(c2m + 1280);
    unsigned short* wtL   = wtPre + 256 * 512;
    unsigned short* wkT   = wtL + 25 * 65536;
    unsigned short* wvT   = wkT + 5 * 4096;
    unsigned short* wqT   = wvT + 5 * 1024;

    unsigned short* wtIn = wtL;
    unsigned short* wtO1 = wtL +  5 * 65536;
    unsigned short* wtO2 = wtL + 10 * 65536;
    unsigned short* wtM1 = wtL + 15 * 65536;
    unsigned short* wtM2 = wtL + 20 * 65536;

    dim3 bt(256);

    transpose_bf16_k<<<dim3(16, 8, 1), bt, 0, stream>>>(pre_w2, wtPre, 512);
    transpose_scale_bf16_k<<<dim3(8, 8, 5), bt, 0, stream>>>(inp_w,  ln1_g, wtIn, 256);
    transpose_bf16_k<<<dim3(8, 8, 5), bt, 0, stream>>>(out_w1, wtO1, 256);
    transpose_bf16_k<<<dim3(8, 8, 5), bt, 0, stream>>>(out_w2, wtO2, 256);
    transpose_scale_bf16_k<<<dim3(8, 8, 5), bt, 0, stream>>>(mlp_w1, ln2_g, wtM1, 256);
    transpose_bf16_k<<<dim3(8, 8, 5), bt, 0, stream>>>(mlp_w2, wtM2, 256);
    colsum_k<<<dim3(1, 1, 5), bt, 0, stream>>>(inp_w,  ln1_g, ln1_b, c2i, c1i);
    colsum_k<<<dim3(1, 1, 5), bt, 0, stream>>>(mlp_w1, ln2_g, ln2_b, c2m, c1m);
    prep_wkvT<<<dim3(5), bt, 0, stream>>>(wk, wv, wq, wkT, wvT, wqT);

    // fused preprocess + layer-0 xm producer:
    //   fx = GELU(x@pre_w1+b1)@pre_w2 + b2 + ph ; xmA = perm(LN(fx)@inp_w0 + b)
    gena_lgl<<<dim3(512), bt, 0, stream>>>(
        x, pre_w1, pre_b1, wtPre, pre_b2, ph, fx,
        wtIn, inp_b, c1i, c2i, xmA);

    for (int i = 0; i < 5; ++i) {
        unsigned short* xmCur  = (i & 1) ? xmB : xmA;
        unsigned short* xmNext = (i & 1) ? xmA : xmB;
        // kv via MFMA (partials in scr) + reduce -> kvT bf16 + se
        kv6_kernel<<<dim3(64, 8), bt, 0, stream>>>(
            xmCur, wkT + (size_t)i * 4096, wvT + (size_t)i * 1024, temp_k, scr, i);
        kv_reduce_kernel<<<dim3(132), bt, 0, stream>>>(scr, kvT, se);
        // fused qkv + attn-out: fx += GELU(qkv @ O1 + b1) @ O2 + b2 (+LN2 stats)
        attn_lgl<<<dim3(512), bt, 0, stream>>>(
            xmCur, wqT + (size_t)i * 4096, temp_q, kvT, se,
            wtO1 + (size_t)i * 65536, out_b1 + i * 256,
            wtO2 + (size_t)i * 65536, out_b2 + i * 256,
            fx, st, i);
        // fused mlp: fx += GELU(LN(fx) @ M1 + b1) @ M2 + b2 ; i<4 also emits next xm2h
        if (i < 4) {
            gemm_lgl<true, true, false, true><<<dim3(512), bt, 0, stream>>>(
                nullptr, fx, wtM1 + (size_t)i * 65536, wtM2 + (size_t)i * 65536,
                mlp_b1 + i * 256, mlp_b2 + i * 256, fx, st, nullptr,
                c1m + i * 256, c2m + i * 256,
                wtIn + (size_t)(i + 1) * 65536, inp_b + (i + 1) * 256,
                c1i + (i + 1) * 256, c2i + (i + 1) * 256, xmNext);
        } else {
            gemm_lgl<true, true, false, false><<<dim3(512), bt, 0, stream>>>(
                nullptr, fx, wtM1 + (size_t)i * 65536, wtM2 + (size_t)i * 65536,
                mlp_b1 + i * 256, mlp_b2 + i * 256, fx, st, nullptr,
                c1m + i * 256, c2m + i * 256,
                nullptr, nullptr, nullptr, nullptr, nullptr);
        }
    }
    head_kernel<<<dim3(NP / 4), bt, 0, stream>>>(fx, ln3_g, ln3_b, head_w, head_b, out);
}

// Round 13
// 796.443 us; speedup vs baseline: 1.4680x; 1.4680x over previous
//
#include <hip/hip_runtime.h>
#include <hip/hip_bf16.h>
#include <math.h>

constexpr int NP  = 32768;  // mesh points
constexpr int HH  = 8;      // heads

typedef short bf16x8 __attribute__((ext_vector_type(8)));
typedef float f32x4  __attribute__((ext_vector_type(4)));

__device__ __forceinline__ float gelu_f(float x) {
    return 0.5f * x * (1.0f + erff(x * 0.70710678118654752f));
}

__device__ __forceinline__ unsigned short f2bf(float x) {
    union { float f; unsigned u; } v; v.f = x;
    unsigned r = v.u + 0x7fffu + ((v.u >> 16) & 1u);
    return (unsigned short)(r >> 16);
}

__device__ __forceinline__ float bf2f(unsigned short h) {
    union { unsigned u; float f; } v; v.u = ((unsigned)h) << 16;
    return v.f;
}

// ---------------------------------------------------------------------------
// Weight prep: src [G][K][256] fp32 -> dst [G][256][K] bf16 (transposed)
// ---------------------------------------------------------------------------
__global__ __launch_bounds__(256) void transpose_bf16_k(
    const float* __restrict__ src, unsigned short* __restrict__ dst, int K)
{
    __shared__ float tile[32][33];
    int g = blockIdx.z;
    int k0 = blockIdx.x * 32, c0 = blockIdx.y * 32;
    int tx = threadIdx.x & 31, ty = threadIdx.x >> 5;
    const float* s = src + (size_t)g * K * 256;
    unsigned short* d = dst + (size_t)g * 256 * K;
    #pragma unroll
    for (int rr = 0; rr < 4; ++rr) {
        int r = ty + rr * 8;
        tile[r][tx] = s[(size_t)(k0 + r) * 256 + c0 + tx];
    }
    __syncthreads();
    #pragma unroll
    for (int rr = 0; rr < 4; ++rr) {
        int r = ty + rr * 8;
        d[(size_t)(c0 + r) * K + k0 + tx] = f2bf(tile[tx][r]);
    }
}

// Same, but scales row k by g[z*256+k] before rounding (LN-fold weights g.W)
__global__ __launch_bounds__(256) void transpose_scale_bf16_k(
    const float* __restrict__ src, const float* __restrict__ g,
    unsigned short* __restrict__ dst, int K)
{
    __shared__ float tile[32][33];
    int z = blockIdx.z;
    int k0 = blockIdx.x * 32, c0 = blockIdx.y * 32;
    int tx = threadIdx.x & 31, ty = threadIdx.x >> 5;
    const float* s = src + (size_t)z * K * 256;
    unsigned short* d = dst + (size_t)z * 256 * K;
    #pragma unroll
    for (int rr = 0; rr < 4; ++rr) {
        int r = ty + rr * 8;
        tile[r][tx] = s[(size_t)(k0 + r) * 256 + c0 + tx];
    }
    __syncthreads();
    float gs = g[z * 256 + k0 + tx];
    #pragma unroll
    for (int rr = 0; rr < 4; ++rr) {
        int r = ty + rr * 8;
        d[(size_t)(c0 + r) * K + k0 + tx] = f2bf(gs * tile[tx][r]);
    }
}

// c2[z][c] = sum_k g[z][k] W[z][k][c] ; c1[z][c] = sum_k b[z][k] W[z][k][c]
__global__ __launch_bounds__(256) void colsum_k(
    const float* __restrict__ W, const float* __restrict__ g,
    const float* __restrict__ b, float* __restrict__ c2, float* __restrict__ c1)
{
    int z = blockIdx.z, c = threadIdx.x;
    const float* Wz = W + (size_t)z * 65536;
    const float* gz = g + z * 256;
    const float* bz = b + z * 256;
    float s2 = 0.f, s1 = 0.f;
    for (int k = 0; k < 256; ++k) {
        float w = Wz[k * 256 + c];
        s2 += gz[k] * w;
        s1 += bz[k] * w;
    }
    c2[z * 256 + c] = s2;
    c1[z * 256 + c] = s1;
}

// wkT[l][d][k]=bf16(wk[l][k][d]); wvT[l][c][k]=bf16(wv[l][k][c]);
// wqT[l][d][k]=bf16(wq[l][k][d])
__global__ __launch_bounds__(256) void prep_wkvT(
    const float* __restrict__ wk, const float* __restrict__ wv,
    const float* __restrict__ wq,
    unsigned short* __restrict__ wkT, unsigned short* __restrict__ wvT,
    unsigned short* __restrict__ wqT)
{
    int l = blockIdx.x, tid = threadIdx.x;
    for (int idx = tid; idx < 4096; idx += 256) {
        int d = idx >> 5, k = idx & 31;
        wkT[l * 4096 + idx] = f2bf(wk[l * 4096 + k * 128 + d]);
        wqT[l * 4096 + idx] = f2bf(wq[l * 4096 + k * 128 + d]);
    }
    for (int idx = tid; idx < 1024; idx += 256) {
        int c = idx >> 5, k = idx & 31;
        wvT[l * 1024 + idx] = f2bf(wv[l * 1024 + k * 32 + c]);
    }
}

// ---------------------------------------------------------------------------
// gena_lgl: fused preprocess + layer-0 xm producer (R7 proven).
// ---------------------------------------------------------------------------
__global__ __launch_bounds__(256) void gena_lgl(
    const float* __restrict__ genx, const float* __restrict__ genw1,
    const float* __restrict__ genb1,
    const unsigned short* __restrict__ W2t, const float* __restrict__ b2,
    const float* __restrict__ ph,
    float* __restrict__ fx,
    const unsigned short* __restrict__ W3t, const float* __restrict__ b3,
    const float* __restrict__ c1n, const float* __restrict__ c2n,
    unsigned short* __restrict__ outNext)
{
    __shared__ __align__(16) unsigned char tpool[32768];  // {w1s,b1s,x3s} -> Ts
    __shared__ __align__(16) unsigned short As[64 * 64];
    __shared__ __align__(16) unsigned short Bs[256 * 64];
    __shared__ float rmean[64];
    __shared__ float rrstd[64];
    __shared__ float ssum[256];
    __shared__ float ssq[256];

    float* w1s = (float*)tpool;                    // 1536 f
    float* b1s = (float*)(tpool + 6144);           // 512 f
    float* x3s = (float*)(tpool + 8192);           // 64 rows * 4
    unsigned short* Ts = (unsigned short*)tpool;   // 64*256 bf16 (post-P1)

    const int tid = threadIdx.x;
    const int rBase = blockIdx.x * 64;
    const int lane = tid & 63, wid = tid >> 6;     // wid = column quarter 0..3
    const int lrow = lane & 15, quad = lane >> 4;

    for (int i2 = tid; i2 < 1536; i2 += 256) w1s[i2] = genw1[i2];
    for (int i2 = tid; i2 < 512; i2 += 256) b1s[i2] = genb1[i2];
    if (tid < 64) {
        x3s[tid * 4 + 0] = genx[(size_t)(rBase + tid) * 3 + 0];
        x3s[tid * 4 + 1] = genx[(size_t)(rBase + tid) * 3 + 1];
        x3s[tid * 4 + 2] = genx[(size_t)(rBase + tid) * 3 + 2];
    }
    __syncthreads();

    // ---- P1: K=512 GEMM with on-the-fly A generation (once per element) ----
    f32x4 acc[4][4];
    #pragma unroll
    for (int i = 0; i < 4; ++i)
        #pragma unroll
        for (int j = 0; j < 4; ++j) acc[i][j] = (f32x4){0.f, 0.f, 0.f, 0.f};

    for (int kc = 0; kc < 512; kc += 64) {
        #pragma unroll
        for (int it = 0; it < 2; ++it) {
            int idx = tid + it * 256;
            int row = idx >> 3, sch = idx & 7;
            float x0 = x3s[row * 4 + 0], x1 = x3s[row * 4 + 1], x2 = x3s[row * 4 + 2];
            unsigned short pk[8];
            #pragma unroll
            for (int j = 0; j < 8; ++j) {
                int k = kc + sch * 8 + j;
                float t = x0 * w1s[k] + x1 * w1s[512 + k] + x2 * w1s[1024 + k] + b1s[k];
                pk[j] = f2bf(gelu_f(t));
            }
            *(uint4*)&As[row * 64 + ((sch ^ (row & 7)) << 3)] = *(uint4*)pk;
        }
        #pragma unroll
        for (int it = 0; it < 8; ++it) {
            int idx = tid + it * 256;
            int n = idx >> 3, sch = idx & 7;
            uint4 wv_ = *(const uint4*)(W2t + (size_t)n * 512 + kc + sch * 8);
            *(uint4*)&Bs[n * 64 + ((sch ^ (n & 7)) << 3)] = wv_;
        }
        __syncthreads();
        #pragma unroll
        for (int ks = 0; ks < 2; ++ks) {
            bf16x8 af[4], bfr[4];
            #pragma unroll
            for (int t = 0; t < 4; ++t) {
                int row = t * 16 + lrow;
                af[t] = *(bf16x8*)&As[row * 64 + (((ks * 4 + quad) ^ (row & 7)) << 3)];
                int n = wid * 64 + t * 16 + lrow;
                bfr[t] = *(bf16x8*)&Bs[n * 64 + (((ks * 4 + quad) ^ (n & 7)) << 3)];
            }
            #pragma unroll
            for (int ti = 0; ti < 4; ++ti)
                #pragma unroll
                for (int tj = 0; tj < 4; ++tj)
                    acc[ti][tj] = __builtin_amdgcn_mfma_f32_16x16x32_bf16(
                        af[ti], bfr[tj], acc[ti][tj], 0, 0, 0);
        }
        __syncthreads();
    }

    // epilogue: fx = acc + (pre_b2 + ph); in-block stats; park bf16 in Ts
    {
        float c1b[4];
        #pragma unroll
        for (int tj = 0; tj < 4; ++tj) {
            int gcol = wid * 64 + tj * 16 + lrow;
            c1b[tj] = b2[gcol] + ph[gcol];
        }
        #pragma unroll
        for (int ti = 0; ti < 4; ++ti) {
            #pragma unroll
            for (int r = 0; r < 4; ++r) {
                int row = ti * 16 + quad * 4 + r;
                int grow = rBase + row;
                float vv[4];
                #pragma unroll
                for (int tj = 0; tj < 4; ++tj)
                    vv[tj] = acc[ti][tj][r] + c1b[tj];
                float rs = vv[0] + vv[1] + vv[2] + vv[3];
                float rq = vv[0]*vv[0] + vv[1]*vv[1] + vv[2]*vv[2] + vv[3]*vv[3];
                #pragma unroll
                for (int m = 1; m < 16; m <<= 1) {
                    rs += __shfl_xor(rs, m);
                    rq += __shfl_xor(rq, m);
                }
                if (lrow == 0) { ssum[row * 4 + wid] = rs; ssq[row * 4 + wid] = rq; }
                #pragma unroll
                for (int tj = 0; tj < 4; ++tj) {
                    int gcol = wid * 64 + tj * 16 + lrow;
                    fx[(size_t)grow * 256 + gcol] = vv[tj];
                    int ch = gcol >> 3;
                    Ts[row * 256 + ((ch ^ (row & 7)) << 3) + (gcol & 7)] = f2bf(vv[tj]);
                }
            }
        }
    }
    __syncthreads();
    if (tid < 64) {
        float mean = (ssum[tid*4+0] + ssum[tid*4+1] + ssum[tid*4+2] + ssum[tid*4+3]) * (1.f/256.f);
        float ex2  = (ssq [tid*4+0] + ssq [tid*4+1] + ssq [tid*4+2] + ssq [tid*4+3]) * (1.f/256.f);
        rmean[tid] = mean;
        rrstd[tid] = rsqrtf(fmaxf(ex2 - mean * mean, 0.f) + 1e-5f);
    }
    __syncthreads();

    // ---- P3: xm0 = LNfold(fx) @ W3 + fold(b3,c1n,c2n), PERM write ----
    f32x4 acc3[4][4];
    #pragma unroll
    for (int i = 0; i < 4; ++i)
        #pragma unroll
        for (int j = 0; j < 4; ++j) acc3[i][j] = (f32x4){0.f, 0.f, 0.f, 0.f};

    for (int kc = 0; kc < 256; kc += 64) {
        #pragma unroll
        for (int it = 0; it < 8; ++it) {
            int idx = tid + it * 256;
            int n = idx >> 3, sch = idx & 7;
            uint4 wv_ = *(const uint4*)(W3t + (size_t)n * 256 + kc + sch * 8);
            *(uint4*)&Bs[n * 64 + ((sch ^ (n & 7)) << 3)] = wv_;
        }
        __syncthreads();
        #pragma unroll
        for (int ks = 0; ks < 2; ++ks) {
            bf16x8 af[4], bfr[4];
            #pragma unroll
            for (int t = 0; t < 4; ++t) {
                int row = t * 16 + lrow;
                int ch = (kc >> 3) + ks * 4 + quad;
                af[t] = *(bf16x8*)&Ts[row * 256 + ((ch ^ (row & 7)) << 3)];
                int n = wid * 64 + t * 16 + lrow;
                bfr[t] = *(bf16x8*)&Bs[n * 64 + (((ks * 4 + quad) ^ (n & 7)) << 3)];
            }
            #pragma unroll
            for (int ti = 0; ti < 4; ++ti)
                #pragma unroll
                for (int tj = 0; tj < 4; ++tj)
                    acc3[ti][tj] = __builtin_amdgcn_mfma_f32_16x16x32_bf16(
                        af[ti], bfr[tj], acc3[ti][tj], 0, 0, 0);
        }
        __syncthreads();
    }

    float c1b3[4], c2r3[4];
    #pragma unroll
    for (int tj = 0; tj < 4; ++tj) {
        int gcol = wid * 64 + tj * 16 + lrow;
        c1b3[tj] = c1n[gcol] + b3[gcol];
        c2r3[tj] = c2n[gcol];
    }
    #pragma unroll
    for (int ti = 0; ti < 4; ++ti) {
        #pragma unroll
        for (int r = 0; r < 4; ++r) {
            int row = ti * 16 + quad * 4 + r;
            int grow = rBase + row;
            float mean = rmean[row], rstd = rrstd[row];
            #pragma unroll
            for (int tj = 0; tj < 4; ++tj) {
                int gcol = wid * 64 + tj * 16 + lrow;
                float t = acc3[ti][tj][r];
                float v = rstd * (t - mean * c2r3[tj]) + c1b3[tj];
                size_t pidx = (size_t)(gcol >> 5) * NP * 32 + (size_t)grow * 32 + (gcol & 31);
                outNext[pidx] = f2bf(v);
            }
        }
    }
}

// ---------------------------------------------------------------------------
// attn_lgl: fused qkv + attn-out pair (R6/R7/R10 proven). Per 64-row block:
//   P0  per-head qkv -> Dt bf16 into Ts (LDS)
//   P1  T1 = GELU(Dt @ O1 + ob1)          (Ts -> Ts)
//   P2  fx += T1 @ O2 + ob2  (+LN2 stats -> global st)
// ---------------------------------------------------------------------------
__global__ __launch_bounds__(256) void attn_lgl(
    const unsigned short* __restrict__ xm, const unsigned short* __restrict__ wqT,
    const float* __restrict__ tq_arr,
    const unsigned short* __restrict__ kvT, const float* __restrict__ sumexp,
    const unsigned short* __restrict__ O1t, const float* __restrict__ ob1,
    const unsigned short* __restrict__ O2t, const float* __restrict__ ob2,
    float* __restrict__ fx, float* __restrict__ stats_out, int layer)
{
    __shared__ __align__(16) unsigned char upool[38912];
    __shared__ __align__(16) unsigned short Ts[64 * 256];

    unsigned short* xs  = (unsigned short*)(upool);           // 64*32
    unsigned short* wqs = (unsigned short*)(upool + 4096);    // 128*32
    unsigned short* kvb = (unsigned short*)(upool + 12288);   // 32*136
    unsigned short* els = (unsigned short*)(upool + 20992);   // 64*136
    float*          ises = (float*)(upool + 38400);           // 128
    unsigned short* Bs  = (unsigned short*)(upool);           // 256*64 (P1/P2)

    const int tid = threadIdx.x;
    const int rBase = blockIdx.x * 64;
    const int lane = tid & 63, wid = tid >> 6;
    const int lrow = lane & 15, quad = lane >> 4;

    // ---- P0: qkv per head -> Ts ----
    #pragma unroll
    for (int it = 0; it < 2; ++it) {           // wq shared across heads
        int cid = tid + it * 256;
        int d = cid >> 2, kc = cid & 3;
        uint4 v = *(const uint4*)(wqT + d * 32 + kc * 8);
        *(uint4*)&wqs[d * 32 + ((kc ^ (d & 3)) << 3)] = v;
    }
    for (int h = 0; h < 8; ++h) {
        if (h) __syncthreads();                // prev head's reads done
        float tq = fminf(fmaxf(tq_arr[layer * 8 + h], 0.1f), 2.0f);
        float invtq = 1.0f / tq;
        if (tid < 128) ises[tid] = 1.0f / sumexp[h * 128 + tid];
        #pragma unroll
        for (int it = 0; it < 2; ++it) {
            int cid = tid + it * 256;
            int c = cid >> 4, k8 = cid & 15;
            uint4 v = *(const uint4*)(kvT + (size_t)h * 4096 + c * 128 + k8 * 8);
            *(uint4*)&kvb[c * 136 + k8 * 8] = v;
        }
        {
            int row = tid >> 2, kc = tid & 3;
            uint4 v = *(const uint4*)(xm + (size_t)h * NP * 32 +
                                      (size_t)(rBase + row) * 32 + kc * 8);
            *(uint4*)&xs[row * 32 + ((kc ^ (row & 3)) << 3)] = v;
        }
        __syncthreads();

        int arow = wid * 16 + lrow;
        bf16x8 ax = *(bf16x8*)&xs[arow * 32 + ((quad ^ (arow & 3)) << 3)];
        f32x4 lg[8];
        #pragma unroll
        for (int dt = 0; dt < 8; ++dt) {
            int d = dt * 16 + lrow;
            bf16x8 bw = *(bf16x8*)&wqs[d * 32 + ((quad ^ (d & 3)) << 3)];
            f32x4 cc = (f32x4){0.f, 0.f, 0.f, 0.f};
            lg[dt] = __builtin_amdgcn_mfma_f32_16x16x32_bf16(ax, bw, cc, 0, 0, 0);
        }
        float isv[8];
        #pragma unroll
        for (int dt = 0; dt < 8; ++dt) isv[dt] = ises[dt * 16 + lrow];

        #pragma unroll
        for (int r = 0; r < 4; ++r) {
            float m = lg[0][r];
            #pragma unroll
            for (int dt = 1; dt < 8; ++dt) m = fmaxf(m, lg[dt][r]);
            m = fmaxf(m, __shfl_xor(m, 1));
            m = fmaxf(m, __shfl_xor(m, 2));
            m = fmaxf(m, __shfl_xor(m, 4));
            m = fmaxf(m, __shfl_xor(m, 8));
            float e[8], s = 0.f;
            #pragma unroll
            for (int dt = 0; dt < 8; ++dt) {
                e[dt] = __expf((lg[dt][r] - m) * invtq);
                s += e[dt];
            }
            s += __shfl_xor(s, 1);
            s += __shfl_xor(s, 2);
            s += __shfl_xor(s, 4);
            s += __shfl_xor(s, 8);
            float inv = 1.0f / s;
            int erow = wid * 16 + quad * 4 + r;
            #pragma unroll
            for (int dt = 0; dt < 8; ++dt)
                els[erow * 136 + dt * 16 + lrow] = f2bf(e[dt] * inv * isv[dt]);
        }

        #pragma unroll
        for (int ct = 0; ct < 2; ++ct) {
            f32x4 oc = (f32x4){0.f, 0.f, 0.f, 0.f};
            #pragma unroll
            for (int ks = 0; ks < 4; ++ks) {
                bf16x8 ae = *(bf16x8*)&els[(wid * 16 + lrow) * 136 + ks * 32 + quad * 8];
                bf16x8 bv = *(bf16x8*)&kvb[(ct * 16 + lrow) * 136 + ks * 32 + quad * 8];
                oc = __builtin_amdgcn_mfma_f32_16x16x32_bf16(ae, bv, oc, 0, 0, 0);
            }
            #pragma unroll
            for (int r = 0; r < 4; ++r) {
                int row = wid * 16 + quad * 4 + r;
                int col = h * 32 + ct * 16 + lrow;
                int ch = col >> 3;
                Ts[row * 256 + ((ch ^ (row & 7)) << 3) + (col & 7)] = f2bf(oc[r]);
            }
        }
    }
    __syncthreads();

    // ---- shared GEMM phase: acc += Ts(bf16) @ Wt ----
    auto gemm_phase = [&](const unsigned short* __restrict__ Wt, f32x4 (&acc)[4][4]) {
        for (int kc = 0; kc < 256; kc += 64) {
            #pragma unroll
            for (int it = 0; it < 8; ++it) {
                int idx = tid + it * 256;
                int n = idx >> 3, sch = idx & 7;
                uint4 wv_ = *(const uint4*)(Wt + (size_t)n * 256 + kc + sch * 8);
                *(uint4*)&Bs[n * 64 + ((sch ^ (n & 7)) << 3)] = wv_;
            }
            __syncthreads();
            #pragma unroll
            for (int ks = 0; ks < 2; ++ks) {
                bf16x8 af[4], bfr[4];
                #pragma unroll
                for (int t = 0; t < 4; ++t) {
                    int row = t * 16 + lrow;
                    int ch = (kc >> 3) + ks * 4 + quad;
                    af[t] = *(bf16x8*)&Ts[row * 256 + ((ch ^ (row & 7)) << 3)];
                    int n = wid * 64 + t * 16 + lrow;
                    bfr[t] = *(bf16x8*)&Bs[n * 64 + (((ks * 4 + quad) ^ (n & 7)) << 3)];
                }
                #pragma unroll
                for (int ti = 0; ti < 4; ++ti)
                    #pragma unroll
                    for (int tj = 0; tj < 4; ++tj)
                        acc[ti][tj] = __builtin_amdgcn_mfma_f32_16x16x32_bf16(
                            af[ti], bfr[tj], acc[ti][tj], 0, 0, 0);
            }
            __syncthreads();
        }
    };

    // ---- P1: T1 = GELU(Dt @ O1 + ob1) ----
    f32x4 acc[4][4];
    #pragma unroll
    for (int i = 0; i < 4; ++i)
        #pragma unroll
        for (int j = 0; j < 4; ++j) acc[i][j] = (f32x4){0.f, 0.f, 0.f, 0.f};
    gemm_phase(O1t, acc);
    {
        float c1b[4];
        #pragma unroll
        for (int tj = 0; tj < 4; ++tj) c1b[tj] = ob1[wid * 64 + tj * 16 + lrow];
        #pragma unroll
        for (int ti = 0; ti < 4; ++ti) {
            #pragma unroll
            for (int r = 0; r < 4; ++r) {
                int row = ti * 16 + quad * 4 + r;
                #pragma unroll
                for (int tj = 0; tj < 4; ++tj) {
                    float v = gelu_f(acc[ti][tj][r] + c1b[tj]);
                    int col = wid * 64 + tj * 16 + lrow;
                    int ch = col >> 3;
                    Ts[row * 256 + ((ch ^ (row & 7)) << 3) + (col & 7)] = f2bf(v);
                }
            }
        }
    }
    __syncthreads();

    // ---- P2: fx += T1 @ O2 + ob2 (+LN2 stats -> global) ----
    #pragma unroll
    for (int i = 0; i < 4; ++i)
        #pragma unroll
        for (int j = 0; j < 4; ++j) acc[i][j] = (f32x4){0.f, 0.f, 0.f, 0.f};
    gemm_phase(O2t, acc);
    {
        float bb[4];
        #pragma unroll
        for (int tj = 0; tj < 4; ++tj) bb[tj] = ob2[wid * 64 + tj * 16 + lrow];
        #pragma unroll
        for (int ti = 0; ti < 4; ++ti) {
            #pragma unroll
            for (int r = 0; r < 4; ++r) {
                int row = ti * 16 + quad * 4 + r;
                int grow = rBase + row;
                float vv[4];
                #pragma unroll
                for (int tj = 0; tj < 4; ++tj) {
                    int gcol = wid * 64 + tj * 16 + lrow;
                    vv[tj] = acc[ti][tj][r] + bb[tj] + fx[(size_t)grow * 256 + gcol];
                }
                float rs = vv[0] + vv[1] + vv[2] + vv[3];
                float rq = vv[0]*vv[0] + vv[1]*vv[1] + vv[2]*vv[2] + vv[3]*vv[3];
                #pragma unroll
                for (int m = 1; m < 16; m <<= 1) {
                    rs += __shfl_xor(rs, m);
                    rq += __shfl_xor(rq, m);
                }
                if (lrow == 0) {
                    stats_out[(size_t)grow * 8 + wid * 2 + 0] = rs;
                    stats_out[(size_t)grow * 8 + wid * 2 + 1] = rq;
                }
                #pragma unroll
                for (int tj = 0; tj < 4; ++tj) {
                    int gcol = wid * 64 + tj * 16 + lrow;
                    fx[(size_t)grow * 256 + gcol] = vv[tj];
                }
            }
        }
    }
}

// ---------------------------------------------------------------------------
// Fused Linear->GELU->Linear (+ optional next-layer xm2h producer) — R3 proven.
//   fx += GELU((LN?)A @ W1 + b1) @ W2 + b2          [phase 1+2]
//   if NEXTW: xm2h = perm(LNfold(fx) @ W3 + b3)      [phase 3, in-block LN]
// ---------------------------------------------------------------------------
template<bool AF32, bool LNFOLD, bool WSTATS, bool NEXTW>
__global__ __launch_bounds__(256) void gemm_lgl(
    const unsigned short* __restrict__ Ah, const float* __restrict__ Af,
    const unsigned short* __restrict__ W1t, const unsigned short* __restrict__ W2t,
    const float* __restrict__ b1, const float* __restrict__ b2,
    float* __restrict__ fx,
    const float* __restrict__ stats_in, float* __restrict__ stats_out,
    const float* __restrict__ c1v, const float* __restrict__ c2vec,
    const unsigned short* __restrict__ W3t, const float* __restrict__ b3,
    const float* __restrict__ c1n, const float* __restrict__ c2n,
    unsigned short* __restrict__ outNext)
{
    __shared__ __align__(16) unsigned short As[64 * 64];
    __shared__ __align__(16) unsigned short Bs[256 * 64];
    __shared__ __align__(16) unsigned short Ts[64 * 256];
    __shared__ float rmean[(LNFOLD || NEXTW) ? 64 : 1];
    __shared__ float rrstd[(LNFOLD || NEXTW) ? 64 : 1];
    __shared__ float ssum[NEXTW ? 256 : 1];
    __shared__ float ssq [NEXTW ? 256 : 1];

    const int tid = threadIdx.x;
    const int rBase = blockIdx.x * 64;
    const int lane = tid & 63, wid = tid >> 6;   // wid = column quarter 0..3
    const int lrow = lane & 15, quad = lane >> 4;

    if constexpr (LNFOLD) {
        if (tid < 64) {
            const float* sp = stats_in + (size_t)(rBase + tid) * 8;
            float4 s0 = *(const float4*)sp;
            float4 s1 = *(const float4*)(sp + 4);
            float mean = (s0.x + s0.z + s1.x + s1.z) * (1.f / 256.f);
            float ex2  = (s0.y + s0.w + s1.y + s1.w) * (1.f / 256.f);
            rmean[tid] = mean;
            rrstd[tid] = rsqrtf(fmaxf(ex2 - mean * mean, 0.f) + 1e-5f);
        }
    }

    f32x4 acc[4][4];
    #pragma unroll
    for (int i = 0; i < 4; ++i)
        #pragma unroll
        for (int j = 0; j < 4; ++j)
            acc[i][j] = (f32x4){0.f, 0.f, 0.f, 0.f};

    // ---- phase 1: T = GELU((LN?)A @ W1 + b1) ----
    for (int kc = 0; kc < 256; kc += 64) {
        #pragma unroll
        for (int it = 0; it < 2; ++it) {
            int idx = tid + it * 256;
            int row = idx >> 3, sch = idx & 7;
            if constexpr (AF32) {
                const float* ap = Af + (size_t)(rBase + row) * 256 + kc + sch * 8;
                float4 a0 = *(const float4*)ap;
                float4 a1 = *(const float4*)(ap + 4);
                unsigned short pk[8];
                pk[0] = f2bf(a0.x); pk[1] = f2bf(a0.y); pk[2] = f2bf(a0.z); pk[3] = f2bf(a0.w);
                pk[4] = f2bf(a1.x); pk[5] = f2bf(a1.y); pk[6] = f2bf(a1.z); pk[7] = f2bf(a1.w);
                *(uint4*)&As[row * 64 + ((sch ^ (row & 7)) << 3)] = *(uint4*)pk;
            } else {
                uint4 av = *(const uint4*)(Ah + (size_t)(rBase + row) * 256 + kc + sch * 8);
                *(uint4*)&As[row * 64 + ((sch ^ (row & 7)) << 3)] = av;
            }
        }
        #pragma unroll
        for (int it = 0; it < 8; ++it) {
            int idx = tid + it * 256;
            int n = idx >> 3, sch = idx & 7;
            uint4 wv_ = *(const uint4*)(W1t + (size_t)n * 256 + kc + sch * 8);
            *(uint4*)&Bs[n * 64 + ((sch ^ (n & 7)) << 3)] = wv_;
        }
        __syncthreads();
        #pragma unroll
        for (int ks = 0; ks < 2; ++ks) {
            bf16x8 af[4], bfr[4];
            #pragma unroll
            for (int t = 0; t < 4; ++t) {
                int row = t * 16 + lrow;
                af[t] = *(bf16x8*)&As[row * 64 + (((ks * 4 + quad) ^ (row & 7)) << 3)];
                int n = wid * 64 + t * 16 + lrow;
                bfr[t] = *(bf16x8*)&Bs[n * 64 + (((ks * 4 + quad) ^ (n & 7)) << 3)];
            }
            #pragma unroll
            for (int ti = 0; ti < 4; ++ti)
                #pragma unroll
                for (int tj = 0; tj < 4; ++tj)
                    acc[ti][tj] = __builtin_amdgcn_mfma_f32_16x16x32_bf16(
                        af[ti], bfr[tj], acc[ti][tj], 0, 0, 0);
        }
        __syncthreads();
    }

    // epilogue 1: bias (+LN-fold) + GELU -> Ts (bf16, chunk-XOR swizzled)
    {
        float c1b[4], c2r[4];
        #pragma unroll
        for (int tj = 0; tj < 4; ++tj) {
            int gcol = wid * 64 + tj * 16 + lrow;
            if constexpr (LNFOLD) {
                c1b[tj] = c1v[gcol] + b1[gcol];
                c2r[tj] = c2vec[gcol];
            } else {
                c1b[tj] = b1[gcol];
                c2r[tj] = 0.f;
            }
        }
        #pragma unroll
        for (int ti = 0; ti < 4; ++ti) {
            #pragma unroll
            for (int r = 0; r < 4; ++r) {
                int row = ti * 16 + quad * 4 + r;
                float mean = 0.f, rstd = 1.f;
                if constexpr (LNFOLD) { mean = rmean[row]; rstd = rrstd[row]; }
                #pragma unroll
                for (int tj = 0; tj < 4; ++tj) {
                    float t = acc[ti][tj][r];
                    float v;
                    if constexpr (LNFOLD) v = rstd * (t - mean * c2r[tj]) + c1b[tj];
                    else                  v = t + c1b[tj];
                    v = gelu_f(v);
                    int col = wid * 64 + tj * 16 + lrow;
                    int ch = col >> 3;
                    Ts[row * 256 + ((ch ^ (row & 7)) << 3) + (col & 7)] = f2bf(v);
                }
            }
        }
    }
    __syncthreads();

    // ---- phase 2: out = T @ W2 + b2 (+resid); A comes from LDS ----
    f32x4 acc2[4][4];
    #pragma unroll
    for (int i = 0; i < 4; ++i)
        #pragma unroll
        for (int j = 0; j < 4; ++j)
            acc2[i][j] = (f32x4){0.f, 0.f, 0.f, 0.f};

    for (int kc = 0; kc < 256; kc += 64) {
        #pragma unroll
        for (int it = 0; it < 8; ++it) {
            int idx = tid + it * 256;
            int n = idx >> 3, sch = idx & 7;
            uint4 wv_ = *(const uint4*)(W2t + (size_t)n * 256 + kc + sch * 8);
            *(uint4*)&Bs[n * 64 + ((sch ^ (n & 7)) << 3)] = wv_;
        }
        __syncthreads();
        #pragma unroll
        for (int ks = 0; ks < 2; ++ks) {
            bf16x8 af[4], bfr[4];
            #pragma unroll
            for (int t = 0; t < 4; ++t) {
                int row = t * 16 + lrow;
                int ch = (kc >> 3) + ks * 4 + quad;
                af[t] = *(bf16x8*)&Ts[row * 256 + ((ch ^ (row & 7)) << 3)];
                int n = wid * 64 + t * 16 + lrow;
                bfr[t] = *(bf16x8*)&Bs[n * 64 + (((ks * 4 + quad) ^ (n & 7)) << 3)];
            }
            #pragma unroll
            for (int ti = 0; ti < 4; ++ti)
                #pragma unroll
                for (int tj = 0; tj < 4; ++tj)
                    acc2[ti][tj] = __builtin_amdgcn_mfma_f32_16x16x32_bf16(
                        af[ti], bfr[tj], acc2[ti][tj], 0, 0, 0);
        }
        __syncthreads();
    }

    // epilogue 2: +b2, +resid(fx), store fx fp32; optional stats (global or LDS)
    float bb[4];
    #pragma unroll
    for (int tj = 0; tj < 4; ++tj) bb[tj] = b2[wid * 64 + tj * 16 + lrow];
    #pragma unroll
    for (int ti = 0; ti < 4; ++ti) {
        #pragma unroll
        for (int r = 0; r < 4; ++r) {
            int row = ti * 16 + quad * 4 + r;
            int grow = rBase + row;
            float vv[4];
            #pragma unroll
            for (int tj = 0; tj < 4; ++tj) {
                int gcol = wid * 64 + tj * 16 + lrow;
                vv[tj] = acc2[ti][tj][r] + bb[tj] + fx[(size_t)grow * 256 + gcol];
            }
            if constexpr (WSTATS || NEXTW) {
                float rs = vv[0] + vv[1] + vv[2] + vv[3];
                float rq = vv[0]*vv[0] + vv[1]*vv[1] + vv[2]*vv[2] + vv[3]*vv[3];
                #pragma unroll
                for (int m = 1; m < 16; m <<= 1) {
                    rs += __shfl_xor(rs, m);
                    rq += __shfl_xor(rq, m);
                }
                if (lrow == 0) {
                    if constexpr (WSTATS) {
                        stats_out[(size_t)grow * 8 + wid * 2 + 0] = rs;
                        stats_out[(size_t)grow * 8 + wid * 2 + 1] = rq;
                    }
                    if constexpr (NEXTW) {
                        ssum[row * 4 + wid] = rs;
                        ssq [row * 4 + wid] = rq;
                    }
                }
            }
            #pragma unroll
            for (int tj = 0; tj < 4; ++tj) {
                int gcol = wid * 64 + tj * 16 + lrow;
                fx[(size_t)grow * 256 + gcol] = vv[tj];
                if constexpr (NEXTW) {
                    int ch = gcol >> 3;
                    Ts[row * 256 + ((ch ^ (row & 7)) << 3) + (gcol & 7)] = f2bf(vv[tj]);
                }
            }
        }
    }

    if constexpr (NEXTW) {
        __syncthreads();
        if (tid < 64) {
            float mean = (ssum[tid*4+0] + ssum[tid*4+1] + ssum[tid*4+2] + ssum[tid*4+3]) * (1.f/256.f);
            float ex2  = (ssq [tid*4+0] + ssq [tid*4+1] + ssq [tid*4+2] + ssq [tid*4+3]) * (1.f/256.f);
            rmean[tid] = mean;
            rrstd[tid] = rsqrtf(fmaxf(ex2 - mean * mean, 0.f) + 1e-5f);
        }
        __syncthreads();

        // ---- phase 3: xm2h = LNfold(fx) @ W3 + fold(b3,c1n,c2n), PERM write ----
        f32x4 acc3[4][4];
        #pragma unroll
        for (int i = 0; i < 4; ++i)
            #pragma unroll
            for (int j = 0; j < 4; ++j)
                acc3[i][j] = (f32x4){0.f, 0.f, 0.f, 0.f};

        for (int kc = 0; kc < 256; kc += 64) {
            #pragma unroll
            for (int it = 0; it < 8; ++it) {
                int idx = tid + it * 256;
                int n = idx >> 3, sch = idx & 7;
                uint4 wv_ = *(const uint4*)(W3t + (size_t)n * 256 + kc + sch * 8);
                *(uint4*)&Bs[n * 64 + ((sch ^ (n & 7)) << 3)] = wv_;
            }
            __syncthreads();
            #pragma unroll
            for (int ks = 0; ks < 2; ++ks) {
                bf16x8 af[4], bfr[4];
                #pragma unroll
                for (int t = 0; t < 4; ++t) {
                    int row = t * 16 + lrow;
                    int ch = (kc >> 3) + ks * 4 + quad;
                    af[t] = *(bf16x8*)&Ts[row * 256 + ((ch ^ (row & 7)) << 3)];
                    int n = wid * 64 + t * 16 + lrow;
                    bfr[t] = *(bf16x8*)&Bs[n * 64 + (((ks * 4 + quad) ^ (n & 7)) << 3)];
                }
                #pragma unroll
                for (int ti = 0; ti < 4; ++ti)
                    #pragma unroll
                    for (int tj = 0; tj < 4; ++tj)
                        acc3[ti][tj] = __builtin_amdgcn_mfma_f32_16x16x32_bf16(
                            af[ti], bfr[tj], acc3[ti][tj], 0, 0, 0);
            }
            __syncthreads();
        }

        float c1b3[4], c2r3[4];
        #pragma unroll
        for (int tj = 0; tj < 4; ++tj) {
            int gcol = wid * 64 + tj * 16 + lrow;
            c1b3[tj] = c1n[gcol] + b3[gcol];
            c2r3[tj] = c2n[gcol];
        }
        #pragma unroll
        for (int ti = 0; ti < 4; ++ti) {
            #pragma unroll
            for (int r = 0; r < 4; ++r) {
                int row = ti * 16 + quad * 4 + r;
                int grow = rBase + row;
                float mean = rmean[row], rstd = rrstd[row];
                #pragma unroll
                for (int tj = 0; tj < 4; ++tj) {
                    int gcol = wid * 64 + tj * 16 + lrow;
                    float t = acc3[ti][tj][r];
                    float v = rstd * (t - mean * c2r3[tj]) + c1b3[tj];
                    size_t pidx = (size_t)(gcol >> 5) * NP * 32 + (size_t)grow * 32 + (gcol & 31);
                    outNext[pidx] = f2bf(v);
                }
            }
        }
    }
}

// ---------------------------------------------------------------------------
// kv6 (unchanged, working): flash-style MFMA kv.
// ---------------------------------------------------------------------------
__global__ __launch_bounds__(256) void kv6_kernel(
    const unsigned short* __restrict__ xm2h, const unsigned short* __restrict__ wkT,
    const unsigned short* __restrict__ wvT, const float* __restrict__ tk_arr,
    float* __restrict__ partials, int layer)
{
    __shared__ __align__(16) unsigned short xs[64 * 32];
    __shared__ __align__(16) unsigned short wks[128 * 32];
    __shared__ __align__(16) unsigned short wvs[32 * 32];
    __shared__ __align__(16) unsigned short els[128 * 72];
    __shared__ __align__(16) unsigned short vls[32 * 72];
    __shared__ float sums[4 * 128];

    const int tid = threadIdx.x;
    const int h = blockIdx.y;
    const int rowBase = blockIdx.x * 512;
    const int w = tid >> 6, lane = tid & 63;
    const int lrow = lane & 15, quad = lane >> 4;

    float tk = fminf(fmaxf(tk_arr[layer * 8 + h], 0.1f), 2.0f);
    float invtk = 1.0f / tk;

    #pragma unroll
    for (int it = 0; it < 2; ++it) {
        int cid = tid + it * 256;
        int d = cid >> 2, kc = cid & 3;
        uint4 v = *(const uint4*)(wkT + d * 32 + kc * 8);
        *(uint4*)&wks[d * 32 + ((kc ^ (d & 3)) << 3)] = v;
    }
    if (tid < 128) {
        int c = tid >> 2, kc = tid & 3;
        uint4 v = *(const uint4*)(wvT + c * 32 + kc * 8);
        *(uint4*)&wvs[c * 32 + ((kc ^ (c & 3)) << 3)] = v;
    }

    f32x4 acc2[2][2];
    #pragma unroll
    for (int di = 0; di < 2; ++di)
        #pragma unroll
        for (int ci = 0; ci < 2; ++ci)
            acc2[di][ci] = (f32x4){0.f, 0.f, 0.f, 0.f};
    float seacc[8];
    #pragma unroll
    for (int dt = 0; dt < 8; ++dt) seacc[dt] = 0.f;

    const unsigned short* src = xm2h + (size_t)h * NP * 32 + (size_t)rowBase * 32;

    for (int sub = 0; sub < 8; ++sub) {
        __syncthreads();
        {
            int row = tid >> 2, kc = tid & 3;
            uint4 v = *(const uint4*)(src + (size_t)(sub * 64 + row) * 32 + kc * 8);
            *(uint4*)&xs[row * 32 + ((kc ^ (row & 3)) << 3)] = v;
        }
        __syncthreads();
        int arow = w * 16 + lrow;
        bf16x8 ax = *(bf16x8*)&xs[arow * 32 + ((quad ^ (arow & 3)) << 3)];
        #pragma unroll
        for (int ct = 0; ct < 2; ++ct) {
            int c = ct * 16 + lrow;
            bf16x8 bw = *(bf16x8*)&wvs[c * 32 + ((quad ^ (c & 3)) << 3)];
            f32x4 cc = (f32x4){0.f, 0.f, 0.f, 0.f};
            cc = __builtin_amdgcn_mfma_f32_16x16x32_bf16(ax, bw, cc, 0, 0, 0);
            unsigned short pk[4];
            pk[0] = f2bf(cc[0]); pk[1] = f2bf(cc[1]);
            pk[2] = f2bf(cc[2]); pk[3] = f2bf(cc[3]);
            *(uint2*)&vls[(ct * 16 + lrow) * 72 + w * 16 + quad * 4] = *(uint2*)pk;
        }
        #pragma unroll
        for (int dt = 0; dt < 8; ++dt) {
            int d = dt * 16 + lrow;
            bf16x8 bw = *(bf16x8*)&wks[d * 32 + ((quad ^ (d & 3)) << 3)];
            f32x4 cc = (f32x4){0.f, 0.f, 0.f, 0.f};
            cc = __builtin_amdgcn_mfma_f32_16x16x32_bf16(ax, bw, cc, 0, 0, 0);
            unsigned short pk[4];
            float se = 0.f;
            #pragma unroll
            for (int r = 0; r < 4; ++r) {
                float l = fminf(fmaxf(cc[r] * invtk, -30.f), 30.f);
                unsigned short eb = f2bf(__expf(l));
                pk[r] = eb;
                se += bf2f(eb);
            }
            seacc[dt] += se;
            *(uint2*)&els[d * 72 + w * 16 + quad * 4] = *(uint2*)pk;
        }
        __syncthreads();
        #pragma unroll
        for (int di = 0; di < 2; ++di) {
            int dm = (2 * w + di) * 16 + lrow;
            #pragma unroll
            for (int ks = 0; ks < 2; ++ks) {
                bf16x8 ae = *(bf16x8*)&els[dm * 72 + ks * 32 + quad * 8];
                #pragma unroll
                for (int ci = 0; ci < 2; ++ci) {
                    int cn = ci * 16 + lrow;
                    bf16x8 bv = *(bf16x8*)&vls[cn * 72 + ks * 32 + quad * 8];
                    acc2[di][ci] = __builtin_amdgcn_mfma_f32_16x16x32_bf16(
                        ae, bv, acc2[di][ci], 0, 0, 0);
                }
            }
        }
    }

    float* outp = partials + ((size_t)h * 64 + blockIdx.x) * 4224;
    #pragma unroll
    for (int di = 0; di < 2; ++di)
        #pragma unroll
        for (int ci = 0; ci < 2; ++ci)
            #pragma unroll
            for (int r = 0; r < 4; ++r) {
                int d = (2 * w + di) * 16 + quad * 4 + r;
                int c = ci * 16 + lrow;
                outp[d * 32 + c] = acc2[di][ci][r];
            }
    #pragma unroll
    for (int dt = 0; dt < 8; ++dt) {
        float s = seacc[dt];
        s += __shfl_xor(s, 16);
        s += __shfl_xor(s, 32);
        if (quad == 0) sums[w * 128 + dt * 16 + lrow] = s;
    }
    __syncthreads();
    if (tid < 128)
        outp[4096 + tid] = sums[tid] + sums[128 + tid] + sums[256 + tid] + sums[384 + tid];
}

// kv_reduce: emits bf16 kvT[h][c][d] (for qkv's B operand) + sumexp.
__global__ __launch_bounds__(256) void kv_reduce_kernel(
    const float* __restrict__ partials, unsigned short* __restrict__ kvT,
    float* __restrict__ sumexp)
{
    int gid = blockIdx.x * 256 + threadIdx.x;
    if (gid >= 8 * 4224) return;
    int h = gid / 4224, idx = gid % 4224;
    const float* base = partials + (size_t)h * 64 * 4224 + idx;
    float s = 0.f;
    #pragma unroll 8
    for (int c = 0; c < 64; ++c) s += base[(size_t)c * 4224];
    if (idx < 4096) {
        int d = idx >> 5, c = idx & 31;
        kvT[(size_t)h * 4096 + c * 128 + d] = f2bf(s);
    } else {
        sumexp[h * 128 + (idx - 4096)] = s;
    }
}

// ---------------------------------------------------------------------------
// head: out[n] = LN(fx[n]; ln3) . head_w + head_b
// ---------------------------------------------------------------------------
__global__ __launch_bounds__(256) void head_kernel(
    const float* __restrict__ fx, const float* __restrict__ g, const float* __restrict__ b,
    const float* __restrict__ hw, const float* __restrict__ hb, float* __restrict__ out)
{
    int lane = threadIdx.x & 63;
    int row = blockIdx.x * 4 + (threadIdx.x >> 6);
    float4 v = *(const float4*)(fx + (size_t)row * 256 + lane * 4);
    float s1 = v.x + v.y + v.z + v.w;
    float s2 = v.x * v.x + v.y * v.y + v.z * v.z + v.w * v.w;
    #pragma unroll
    for (int m = 1; m < 64; m <<= 1) { s1 += __shfl_xor(s1, m); s2 += __shfl_xor(s2, m); }
    float mean = s1 * 0.00390625f;
    float rstd = rsqrtf(fmaxf(s2 * 0.00390625f - mean * mean, 0.f) + 1e-5f);
    float4 gg = *(const float4*)(g + lane * 4);
    float4 bb = *(const float4*)(b + lane * 4);
    float4 w4 = *(const float4*)(hw + lane * 4);
    float d = ((v.x - mean) * rstd * gg.x + bb.x) * w4.x
            + ((v.y - mean) * rstd * gg.y + bb.y) * w4.y
            + ((v.z - mean) * rstd * gg.z + bb.z) * w4.z
            + ((v.w - mean) * rstd * gg.w + bb.w) * w4.w;
    #pragma unroll
    for (int m = 1; m < 64; m <<= 1) d += __shfl_xor(d, m);
    if (lane == 0) out[row] = d + hb[0];
}

extern "C" void kernel_launch(void* const* d_in, const int* in_sizes, int n_in,
                              void* d_out, int out_size, void* d_ws, size_t ws_size,
                              hipStream_t stream)
{
    const float* x      = (const float*)d_in[0];
    const float* pre_w1 = (const float*)d_in[1];
    const float* pre_b1 = (const float*)d_in[2];
    const float* pre_w2 = (const float*)d_in[3];
    const float* pre_b2 = (const float*)d_in[4];
    const float* ph     = (const float*)d_in[5];
    const float* ln1_g  = (const float*)d_in[6];
    const float* ln1_b  = (const float*)d_in[7];
    const float* inp_w  = (const float*)d_in[8];
    const float* inp_b  = (const float*)d_in[9];
    const float* temp_q = (const float*)d_in[10];
    const float* temp_k = (const float*)d_in[11];
    const float* wq     = (const float*)d_in[12];
    const float* wk     = (const float*)d_in[13];
    const float* wv     = (const float*)d_in[14];
    const float* out_w1 = (const float*)d_in[15];
    const float* out_b1 = (const float*)d_in[16];
    const float* out_w2 = (const float*)d_in[17];
    const float* out_b2 = (const float*)d_in[18];
    const float* ln2_g  = (const float*)d_in[19];
    const float* ln2_b  = (const float*)d_in[20];
    const float* mlp_w1 = (const float*)d_in[21];
    const float* mlp_b1 = (const float*)d_in[22];
    const float* mlp_w2 = (const float*)d_in[23];
    const float* mlp_b2 = (const float*)d_in[24];
    const float* ln3_g  = (const float*)d_in[25];
    const float* ln3_b  = (const float*)d_in[26];
    const float* head_w = (const float*)d_in[27];
    const float* head_b = (const float*)d_in[28];
    float* out = (float*)d_out;

    // ws layout: fx | xmB | xmA | scr | st | kvT | se | cvecs | weights
    float* fx = (float*)d_ws;
    unsigned short* xmB = (unsigned short*)(fx + (size_t)NP * 256);
    unsigned short* xmA = xmB + (size_t)NP * 256;
    float* scr = (float*)(xmA + (size_t)NP * 256);
    float* st = scr + (size_t)NP * 256;
    unsigned short* kvT = (unsigned short*)(st + (size_t)NP * 8);
    float* se = (float*)(kvT + 8 * 4096);
    float* c1i = se + 8 * 128;
    float* c2i = c1i + 1280;
    float* c1m = c2i + 1280;
    float* c2m = c1m + 1280;
    unsigned short* wtPre = (unsigned short*)(c2m + 1280);
    unsigned short* wtL   = wtPre + 256 * 512;
    unsigned short* wkT   = wtL + 25 * 65536;
    unsigned short* wvT   = wkT + 5 * 4096;
    unsigned short* wqT   = wvT + 5 * 1024;

    unsigned short* wtIn = wtL;
    unsigned short* wtO1 = wtL +  5 * 65536;
    unsigned short* wtO2 = wtL + 10 * 65536;
    unsigned short* wtM1 = wtL + 15 * 65536;
    unsigned short* wtM2 = wtL + 20 * 65536;

    dim3 bt(256);

    transpose_bf16_k<<<dim3(16, 8, 1), bt, 0, stream>>>(pre_w2, wtPre, 512);
    transpose_scale_bf16_k<<<dim3(8, 8, 5), bt, 0, stream>>>(inp_w,  ln1_g, wtIn, 256);
    transpose_bf16_k<<<dim3(8, 8, 5), bt, 0, stream>>>(out_w1, wtO1, 256);
    transpose_bf16_k<<<dim3(8, 8, 5), bt, 0, stream>>>(out_w2, wtO2, 256);
    transpose_scale_bf16_k<<<dim3(8, 8, 5), bt, 0, stream>>>(mlp_w1, ln2_g, wtM1, 256);
    transpose_bf16_k<<<dim3(8, 8, 5), bt, 0, stream>>>(mlp_w2, wtM2, 256);
    colsum_k<<<dim3(1, 1, 5), bt, 0, stream>>>(inp_w,  ln1_g, ln1_b, c2i, c1i);
    colsum_k<<<dim3(1, 1, 5), bt, 0, stream>>>(mlp_w1, ln2_g, ln2_b, c2m, c1m);
    prep_wkvT<<<dim3(5), bt, 0, stream>>>(wk, wv, wq, wkT, wvT, wqT);

    // fused preprocess + layer-0 xm producer:
    //   fx = GELU(x@pre_w1+b1)@pre_w2 + b2 + ph ; xmA = perm(LN(fx)@inp_w0 + b)
    gena_lgl<<<dim3(512), bt, 0, stream>>>(
        x, pre_w1, pre_b1, wtPre, pre_b2, ph, fx,
        wtIn, inp_b, c1i, c2i, xmA);

    for (int i = 0; i < 5; ++i) {
        unsigned short* xmCur  = (i & 1) ? xmB : xmA;
        unsigned short* xmNext = (i & 1) ? xmA : xmB;
        // kv via MFMA (partials in scr) + reduce -> kvT bf16 + se
        kv6_kernel<<<dim3(64, 8), bt, 0, stream>>>(
            xmCur, wkT + (size_t)i * 4096, wvT + (size_t)i * 1024, temp_k, scr, i);
        kv_reduce_kernel<<<dim3(132), bt, 0, stream>>>(scr, kvT, se);
        // fused qkv + attn-out: fx += GELU(qkv @ O1 + b1) @ O2 + b2 (+LN2 stats)
        attn_lgl<<<dim3(512), bt, 0, stream>>>(
            xmCur, wqT + (size_t)i * 4096, temp_q, kvT, se,
            wtO1 + (size_t)i * 65536, out_b1 + i * 256,
            wtO2 + (size_t)i * 65536, out_b2 + i * 256,
            fx, st, i);
        // fused mlp: fx += GELU(LN(fx) @ M1 + b1) @ M2 + b2 ; i<4 also emits next xm2h
        if (i < 4) {
            gemm_lgl<true, true, false, true><<<dim3(512), bt, 0, stream>>>(
                nullptr, fx, wtM1 + (size_t)i * 65536, wtM2 + (size_t)i * 65536,
                mlp_b1 + i * 256, mlp_b2 + i * 256, fx, st, nullptr,
                c1m + i * 256, c2m + i * 256,
                wtIn + (size_t)(i + 1) * 65536, inp_b + (i + 1) * 256,
                c1i + (i + 1) * 256, c2i + (i + 1) * 256, xmNext);
        } else {
            gemm_lgl<true, true, false, false><<<dim3(512), bt, 0, stream>>>(
                nullptr, fx, wtM1 + (size_t)i * 65536, wtM2 + (size_t)i * 65536,
                mlp_b1 + i * 256, mlp_b2 + i * 256, fx, st, nullptr,
                c1m + i * 256, c2m + i * 256,
                nullptr, nullptr, nullptr, nullptr, nullptr);
        }
    }
    head_kernel<<<dim3(NP / 4), bt, 0, stream>>>(fx, ln3_g, ln3_b, head_w, head_b, out);
}